// Round 10
// baseline (1227.972 us; speedup 1.0000x reference)
//
#include <hip/hip_runtime.h>

#define DEVINL __device__ __forceinline__

typedef __attribute__((ext_vector_type(8))) short bf8v;
typedef __attribute__((ext_vector_type(4))) float f4v;

DEVINL float b2f(unsigned short u){ union{unsigned int i; float f;} x; x.i = ((unsigned int)u)<<16; return x.f; }
DEVINL unsigned short f2b(float f){ union{float f; unsigned int i;} x; x.f = f; unsigned int r = x.i + 0x7FFFu + ((x.i>>16)&1u); return (unsigned short)(r>>16); }
DEVINL float sigf(float v){ return 1.f/(1.f + __expf(-v)); }
DEVINL void unpack8(const uint4 u, float* d){
  d[0]=b2f((unsigned short)(u.x)); d[1]=b2f((unsigned short)(u.x>>16));
  d[2]=b2f((unsigned short)(u.y)); d[3]=b2f((unsigned short)(u.y>>16));
  d[4]=b2f((unsigned short)(u.z)); d[5]=b2f((unsigned short)(u.z>>16));
  d[6]=b2f((unsigned short)(u.w)); d[7]=b2f((unsigned short)(u.w>>16));
}
DEVINL uint4 pack8(const float* s){
  uint4 u;
  u.x = (unsigned int)f2b(s[0]) | ((unsigned int)f2b(s[1])<<16);
  u.y = (unsigned int)f2b(s[2]) | ((unsigned int)f2b(s[3])<<16);
  u.z = (unsigned int)f2b(s[4]) | ((unsigned int)f2b(s[5])<<16);
  u.w = (unsigned int)f2b(s[6]) | ((unsigned int)f2b(s[7])<<16);
  return u;
}
union FragU { uint4 u; bf8v v; };

// B=64 IMG=384 PS=16 DM=96 DS=16 DI=96 DT_RANK=6 NREP=4 NCLS=5 HP=24 N=576, M=36864
//
// Workspace layout chosen AT RUNTIME from ws_size (defensive):
//  big  (ws >= 120.3 MB): fully disjoint buffers; k_patchfull mega-fusion.
//  small (fallback):      R4-proven aliased layout; k_patchln + k_lnfull.
// dt/xs use TRANSPOSED d-major layout: [(b*6+dg)*16+dl][576 t] bf16.
// R9 fix: k_scan token-loops fully unrolled so dts/xss/h stay in VGPRs
// (R8's non-unrolled loops scratch-spilled them: WRITE_SIZE 107 MB, 72 us).

// ---------------- prep ----------------
#define PREP_STRIDE (128*256)
__global__ __launch_bounds__(256) void k_prep(
    const float* __restrict__ Wgate, const float* __restrict__ Win,
    const float* __restrict__ Wxproj, const float* __restrict__ Wdt,
    const float* __restrict__ Wout, const float* __restrict__ Alog,
    const float* __restrict__ Wpe, const float* __restrict__ convw,
    unsigned short* __restrict__ WgT, unsigned short* __restrict__ WiT,
    unsigned short* __restrict__ WxT, unsigned short* __restrict__ WoT,
    float* __restrict__ Amat, unsigned short* __restrict__ WpeB,
    float* __restrict__ cwsplit)
{
  int gtid = blockIdx.x*256 + threadIdx.x;
  for (int i = gtid; i < 9216; i += PREP_STRIDE){
    int n = i/96, k = i - n*96;
    WgT[n*96+k] = f2b(Wgate[k*96+n]);
    WoT[n*96+k] = f2b(Wout[k*96+n]);
  }
  for (int i = gtid; i < 18432; i += PREP_STRIDE){
    int n = i/96, k = i - n*96;
    WiT[n*96+k] = f2b(Win[k*192+n]);
  }
  for (int i = gtid; i < 12288; i += PREP_STRIDE){
    int n = i/96, k = i - n*96;
    if (n < 96){
      float s = 0.f;
      for (int r = 0; r < 6; ++r) s += Wxproj[k*38+r] * Wdt[r*96+n];
      WxT[n*96+k] = f2b(s);
    } else {
      WxT[n*96+k] = f2b(Wxproj[k*38 + 6 + (n-96)]);
    }
  }
  for (int i = gtid; i < 1536; i += PREP_STRIDE) Amat[i] = -__expf(Alog[i]);
  for (int i = gtid; i < 73728; i += PREP_STRIDE) WpeB[i] = f2b(Wpe[i]);
  for (int i = gtid; i < 96; i += PREP_STRIDE){
    cwsplit[i]       = convw[i*3+0];
    cwsplit[96+i]    = convw[i*3+1];
    cwsplit[192+i]   = convw[i*3+2];
  }
}

// ---------------- K1: 5x5 box blur + log1p diff -> xlog (bf16) ----------------
__global__ __launch_bounds__(256) void k_blur(const float* __restrict__ x,
                                              unsigned short* __restrict__ xlog)
{
  __shared__ unsigned short xt[12*384];
  __shared__ float vt[8*392];
  int bid = blockIdx.x;                  // 64*3*48
  int tile = bid % 48; int bc = bid / 48; int c = bc % 3; int b = bc / 3;
  const float* xin = x + (size_t)(b*3 + c) * 147456;
  unsigned short* xout = xlog + (size_t)(b*3 + c) * 147456;
  int y0 = tile * 8;
  int tid = threadIdx.x;

  #pragma unroll
  for (int k = 0; k < 5; ++k){
    int idx = tid + k*256;
    if (idx < 1152){
      int r = idx / 96; int c4 = idx - r*96;
      int gy = y0 - 2 + r;
      float4 v = make_float4(0.f,0.f,0.f,0.f);
      if (gy >= 0 && gy < 384) v = *(const float4*)(xin + gy*384 + c4*4);
      ushort4 o; o.x=f2b(v.x); o.y=f2b(v.y); o.z=f2b(v.z); o.w=f2b(v.w);
      *(ushort4*)(xt + r*384 + c4*4) = o;
    }
  }
  if (tid < 64){
    int r = tid >> 3; int j = tid & 7;
    vt[r*392 + ((j < 4) ? j : (384 + j))] = 0.f;
  }
  __syncthreads();

  #pragma unroll
  for (int k = 0; k < 2; ++k){
    int unit = tid + k*256;
    if (unit < 384){
      int r = unit / 48; int c8 = unit - r*48;
      const unsigned short* base = xt + r*384 + c8*8;
      float acc[8]; float t[8];
      uint4 u0 = *(const uint4*)(base);
      unpack8(u0, acc);
      #pragma unroll
      for (int i = 1; i < 5; ++i){
        uint4 u = *(const uint4*)(base + i*384);
        unpack8(u, t);
        #pragma unroll
        for (int j = 0; j < 8; ++j) acc[j] += t[j];
      }
      float* vrow = vt + r*392 + 4 + c8*8;
      *(float4*)(vrow)   = make_float4(acc[0],acc[1],acc[2],acc[3]);
      *(float4*)(vrow+4) = make_float4(acc[4],acc[5],acc[6],acc[7]);
    }
  }
  __syncthreads();

  #pragma unroll
  for (int k = 0; k < 3; ++k){
    int unit = tid + k*256;
    int r = unit / 96; int c4 = unit - r*96;
    int base = r*392 + 4 + c4*4;
    float f[12];
    *(float4*)(f)   = *(const float4*)(vt + base - 4);
    *(float4*)(f+4) = *(const float4*)(vt + base);
    *(float4*)(f+8) = *(const float4*)(vt + base + 4);
    ushort4 xr = *(const ushort4*)(xt + (r+2)*384 + c4*4);
    const unsigned short* xrp = &xr.x;
    ushort4 o;
    unsigned short* op = &o.x;
    #pragma unroll
    for (int j = 0; j < 4; ++j){
      float s = f[2+j] + f[3+j] + f[4+j] + f[5+j] + f[6+j];
      float L = fmaxf(s * 0.04f, 0.f);
      float xv = fmaxf(b2f(xrp[j]), 0.f);
      op[j] = f2b(__logf(1.f + xv) - __logf(1.f + L));
    }
    *(ushort4*)(xout + (y0+r)*384 + c4*4) = o;
  }
}

// ---------------- K2a (fallback): patch embed + bias + dn-LN + vis ----------------
__global__ __launch_bounds__(256) void k_patchln(
    const unsigned short* __restrict__ xlog, const unsigned short* __restrict__ WpeB,
    const float* __restrict__ bpe, const float* __restrict__ dng,
    const float* __restrict__ dnb, const float* __restrict__ Wvis,
    const float* __restrict__ bvis, float* __restrict__ tok, float* __restrict__ vis)
{
  int wid = threadIdx.x >> 6, lane = threadIdx.x & 63;
  int m0 = (blockIdx.x*4 + wid)*16;
  int l15 = lane & 15, q = lane >> 4;
  int ma0 = m0 + l15;
  int b0 = ma0/576; int r0 = ma0 - b0*576; int hp0 = r0/24; int wp0 = r0 - hp0*24;
  size_t base0 = (size_t)b0*442368 + (size_t)hp0*6144 + (size_t)wp0*16;
  f4v acc[6];
  #pragma unroll
  for (int j=0;j<6;++j)
    #pragma unroll
    for (int r=0;r<4;++r) acc[j][r] = 0.f;
  for (int ks = 0; ks < 24; ++ks){
    int k0 = ks*32 + q*8;
    int c  = k0 >> 8;
    int ph = (k0 >> 4) & 15;
    int pw = k0 & 15;
    size_t off = (size_t)c*147456 + (size_t)ph*384 + pw;
    bf8v a0 = *(const bf8v*)(xlog + base0 + off);
    #pragma unroll
    for (int nf = 0; nf < 6; ++nf){
      bf8v bb = *(const bf8v*)(WpeB + (size_t)(nf*16 + l15)*768 + k0);
      acc[nf] = __builtin_amdgcn_mfma_f32_16x16x32_bf16(a0, bb, acc[nf], 0, 0, 0);
    }
  }
  float v[6][4];
  float s[4], w[4], vd[4];
  #pragma unroll
  for (int r=0;r<4;++r){ s[r]=0.f; w[r]=0.f; vd[r]=0.f; }
  #pragma unroll
  for (int nf=0; nf<6; ++nf){
    int n = nf*16 + l15;
    float bp = bpe[n];
    float wv = Wvis[n];
    #pragma unroll
    for (int r=0;r<4;++r){
      float t = acc[nf][r] + bp;
      v[nf][r] = t;
      s[r] += t; w[r] += t*t; vd[r] += t*wv;
    }
  }
  #pragma unroll
  for (int off=1; off<16; off<<=1){
    #pragma unroll
    for (int r=0;r<4;++r){
      s[r]  += __shfl_xor(s[r],  off);
      w[r]  += __shfl_xor(w[r],  off);
      vd[r] += __shfl_xor(vd[r], off);
    }
  }
  float mu[4], rs[4];
  #pragma unroll
  for (int r=0;r<4;++r){
    mu[r] = s[r]*(1.f/96.f);
    rs[r] = rsqrtf(fmaxf(w[r]*(1.f/96.f)-mu[r]*mu[r], 0.f) + 1e-5f);
  }
  if (l15 == 0){
    #pragma unroll
    for (int r=0;r<4;++r) vis[m0 + q*4 + r] = sigf(vd[r] + bvis[0]);
  }
  #pragma unroll
  for (int nf=0; nf<6; ++nf){
    int n = nf*16 + l15;
    float g = dng[n], bb = dnb[n];
    #pragma unroll
    for (int r=0;r<4;++r)
      tok[(size_t)(m0 + q*4 + r)*96 + n] = (v[nf][r]-mu[r])*rs[r]*g + bb;
  }
}

// ---------------- K2b (fallback): gate GEMM + lnLN + Win GEMM (N-split x2) ------------
__global__ __launch_bounds__(256) void k_lnfull(const float* __restrict__ tokp,
    const unsigned short* __restrict__ WgT, const float* __restrict__ bg,
    const float* __restrict__ lng, const float* __restrict__ lnb,
    const unsigned short* __restrict__ WiT, const float* __restrict__ vis,
    unsigned short* __restrict__ gate, unsigned short* __restrict__ xin,
    unsigned short* __restrict__ zsv)
{
  int wid = threadIdx.x >> 6, lane = threadIdx.x & 63;
  int gid = blockIdx.x*4 + wid;
  int tile = gid >> 1, half = gid & 1;
  int m0 = tile*16;
  int l15 = lane & 15, q = lane >> 4;
  int ma0 = m0 + l15;
  float a0v[24];
  float s1=0.f, w1=0.f;
  bf8v fa[3];
  #pragma unroll
  for (int ks = 0; ks < 3; ++ks){
    int k0 = ks*32 + q*8;
    float v0[8];
    #pragma unroll
    for (int h = 0; h < 2; ++h){
      float4 va = *(const float4*)(tokp + (size_t)ma0*96 + k0 + h*4);
      int o = ks*8 + h*4;
      a0v[o+0]=va.x; a0v[o+1]=va.y; a0v[o+2]=va.z; a0v[o+3]=va.w;
      v0[h*4+0]=va.x; v0[h*4+1]=va.y; v0[h*4+2]=va.z; v0[h*4+3]=va.w;
      s1 += (va.x+va.y)+(va.z+va.w);
      w1 += (va.x*va.x+va.y*va.y)+(va.z*va.z+va.w*va.w);
    }
    FragU U0; U0.u = pack8(v0);
    fa[ks] = U0.v;
  }
  s1 += __shfl_xor(s1, 16); s1 += __shfl_xor(s1, 32);
  w1 += __shfl_xor(w1, 16); w1 += __shfl_xor(w1, 32);
  float mu1 = s1*(1.f/96.f);
  float rs1 = rsqrtf(fmaxf(w1*(1.f/96.f)-mu1*mu1, 0.f) + 1e-5f);
  bf8v fb[3];
  #pragma unroll
  for (int ks = 0; ks < 3; ++ks){
    int k0 = ks*32 + q*8;
    float gv[8], bv[8];
    *(float4*)(gv)   = *(const float4*)(lng + k0);
    *(float4*)(gv+4) = *(const float4*)(lng + k0 + 4);
    *(float4*)(bv)   = *(const float4*)(lnb + k0);
    *(float4*)(bv+4) = *(const float4*)(lnb + k0 + 4);
    float v0[8];
    #pragma unroll
    for (int j = 0; j < 8; ++j)
      v0[j] = (a0v[ks*8+j]-mu1)*rs1*gv[j] + bv[j];
    FragU U0; U0.u = pack8(v0);
    fb[ks] = U0.v;
  }
  {
    f4v ag[3];
    #pragma unroll
    for (int j=0;j<3;++j)
      #pragma unroll
      for (int r=0;r<4;++r) ag[j][r] = 0.f;
    const bf8v* bpg = (const bf8v*)(WgT) + (size_t)l15*12 + q;
    #pragma unroll
    for (int ks = 0; ks < 3; ++ks)
      #pragma unroll
      for (int nf = 0; nf < 3; ++nf){
        bf8v bb = bpg[(half*3+nf)*192 + ks*4];
        ag[nf] = __builtin_amdgcn_mfma_f32_16x16x32_bf16(fa[ks], bb, ag[nf], 0, 0, 0);
      }
    #pragma unroll
    for (int nf=0; nf<3; ++nf)
      #pragma unroll
      for (int r=0; r<4; ++r){
        int m = m0 + q*4 + r;
        int n = (half*3+nf)*16 + l15;
        gate[(size_t)m*96 + n] = f2b(sigf(ag[nf][r] + bg[n]));
      }
  }
  {
    f4v aw[6];
    #pragma unroll
    for (int j=0;j<6;++j)
      #pragma unroll
      for (int r=0;r<4;++r) aw[j][r] = 0.f;
    const bf8v* bpw = (const bf8v*)(WiT) + (size_t)l15*12 + q;
    #pragma unroll
    for (int ks = 0; ks < 3; ++ks)
      #pragma unroll
      for (int nf = 0; nf < 6; ++nf){
        bf8v bb = bpw[(half*6+nf)*192 + ks*4];
        aw[nf] = __builtin_amdgcn_mfma_f32_16x16x32_bf16(fb[ks], bb, aw[nf], 0, 0, 0);
      }
    if (half == 0){
      #pragma unroll
      for (int nf=0; nf<6; ++nf)
        #pragma unroll
        for (int r=0; r<4; ++r){
          int m = m0 + q*4 + r;
          int n = nf*16 + l15;
          xin[(size_t)m*96 + n] = f2b(aw[nf][r]);
        }
    } else {
      #pragma unroll
      for (int nf=0; nf<6; ++nf)
        #pragma unroll
        for (int r=0; r<4; ++r){
          int m = m0 + q*4 + r;
          int n = nf*16 + l15;
          float v = aw[nf][r];
          float sgl = v * sigf(v);
          zsv[(size_t)m*96 + n] = f2b(sgl * vis[m]);
        }
    }
  }
}

// ---------------- K2 (big ws): patch + dnLN + vis + gate GEMM + lnLN + Win GEMM -------
__global__ __launch_bounds__(256) void k_patchfull(
    const unsigned short* __restrict__ xlog, const unsigned short* __restrict__ WpeB,
    const float* __restrict__ bpe,
    const float* __restrict__ dng, const float* __restrict__ dnb,
    const float* __restrict__ Wvis, const float* __restrict__ bvis,
    const unsigned short* __restrict__ WgT, const float* __restrict__ bg,
    const float* __restrict__ lng, const float* __restrict__ lnb,
    const unsigned short* __restrict__ WiT,
    float* __restrict__ tok, unsigned short* __restrict__ gate,
    float* __restrict__ vis, unsigned short* __restrict__ xin,
    unsigned short* __restrict__ zsv)
{
  __shared__ float Sl[2][16][100];
  __shared__ float Vl[2][16];
  int wid = threadIdx.x >> 6, lane = threadIdx.x & 63;
  int gid = blockIdx.x*4 + wid;
  int tile = gid >> 1, half = gid & 1;
  int tl = wid >> 1;
  int m0 = tile*16;
  int l15 = lane & 15, q = lane >> 4;
  int ma0 = m0 + l15;

  {
    int b0 = ma0/576; int r0 = ma0 - b0*576; int hp0 = r0/24; int wp0 = r0 - hp0*24;
    size_t base0 = (size_t)b0*442368 + (size_t)hp0*6144 + (size_t)wp0*16;
    f4v acc[3];
    #pragma unroll
    for (int j=0;j<3;++j)
      #pragma unroll
      for (int r=0;r<4;++r) acc[j][r] = 0.f;
    for (int ks = 0; ks < 24; ++ks){
      int k0 = ks*32 + q*8;
      int c  = k0 >> 8;
      int ph = (k0 >> 4) & 15;
      int pw = k0 & 15;
      size_t off = (size_t)c*147456 + (size_t)ph*384 + pw;
      bf8v a0 = *(const bf8v*)(xlog + base0 + off);
      #pragma unroll
      for (int nf = 0; nf < 3; ++nf){
        bf8v bb = *(const bf8v*)(WpeB + (size_t)((half*3+nf)*16 + l15)*768 + k0);
        acc[nf] = __builtin_amdgcn_mfma_f32_16x16x32_bf16(a0, bb, acc[nf], 0, 0, 0);
      }
    }
    #pragma unroll
    for (int nf=0; nf<3; ++nf)
      #pragma unroll
      for (int r=0; r<4; ++r){
        int n = (half*3+nf)*16 + l15;
        Sl[tl][q*4+r][n] = acc[nf][r] + bpe[n];
      }
  }
  __syncthreads();

  float a0v[24];
  float s0=0.f, w0=0.f, vd=0.f;
  #pragma unroll
  for (int ks = 0; ks < 3; ++ks){
    int k0 = ks*32 + q*8;
    #pragma unroll
    for (int h = 0; h < 2; ++h){
      float4 va = *(const float4*)(&Sl[tl][l15][k0 + h*4]);
      float4 wv = *(const float4*)(Wvis + k0 + h*4);
      int o = ks*8 + h*4;
      a0v[o+0]=va.x; a0v[o+1]=va.y; a0v[o+2]=va.z; a0v[o+3]=va.w;
      s0 += (va.x+va.y)+(va.z+va.w);
      w0 += (va.x*va.x+va.y*va.y)+(va.z*va.z+va.w*va.w);
      vd += (va.x*wv.x+va.y*wv.y)+(va.z*wv.z+va.w*wv.w);
    }
  }
  s0 += __shfl_xor(s0, 16); s0 += __shfl_xor(s0, 32);
  w0 += __shfl_xor(w0, 16); w0 += __shfl_xor(w0, 32);
  vd += __shfl_xor(vd, 16); vd += __shfl_xor(vd, 32);
  float mu0 = s0*(1.f/96.f);
  float rs0 = rsqrtf(fmaxf(w0*(1.f/96.f)-mu0*mu0, 0.f) + 1e-5f);
  if (half == 0 && q == 0){
    float vv = sigf(vd + bvis[0]);
    vis[ma0] = vv;
    Vl[tl][l15] = vv;
  }

  bf8v fa[3];
  float s1=0.f, w1=0.f;
  #pragma unroll
  for (int ks = 0; ks < 3; ++ks){
    int k0 = ks*32 + q*8;
    float gv[8], bv[8];
    *(float4*)(gv)   = *(const float4*)(dng + k0);
    *(float4*)(gv+4) = *(const float4*)(dng + k0 + 4);
    *(float4*)(bv)   = *(const float4*)(dnb + k0);
    *(float4*)(bv+4) = *(const float4*)(dnb + k0 + 4);
    float v0[8];
    #pragma unroll
    for (int j = 0; j < 8; ++j){
      float v = (a0v[ks*8+j]-mu0)*rs0*gv[j] + bv[j];
      v0[j] = v;
      a0v[ks*8+j] = v;
      s1 += v; w1 += v*v;
    }
    if (half == 0){
      *(float4*)(tok + (size_t)ma0*96 + k0)     = make_float4(v0[0],v0[1],v0[2],v0[3]);
      *(float4*)(tok + (size_t)ma0*96 + k0 + 4) = make_float4(v0[4],v0[5],v0[6],v0[7]);
    }
    FragU U0; U0.u = pack8(v0);
    fa[ks] = U0.v;
  }

  {
    f4v ag[3];
    #pragma unroll
    for (int j=0;j<3;++j)
      #pragma unroll
      for (int r=0;r<4;++r) ag[j][r] = 0.f;
    const bf8v* bpg = (const bf8v*)(WgT) + (size_t)l15*12 + q;
    #pragma unroll
    for (int ks = 0; ks < 3; ++ks)
      #pragma unroll
      for (int nf = 0; nf < 3; ++nf){
        bf8v bb = bpg[(half*3+nf)*192 + ks*4];
        ag[nf] = __builtin_amdgcn_mfma_f32_16x16x32_bf16(fa[ks], bb, ag[nf], 0, 0, 0);
      }
    #pragma unroll
    for (int nf=0; nf<3; ++nf)
      #pragma unroll
      for (int r=0; r<4; ++r){
        int m = m0 + q*4 + r;
        int n = (half*3+nf)*16 + l15;
        gate[(size_t)m*96 + n] = f2b(sigf(ag[nf][r] + bg[n]));
      }
  }

  s1 += __shfl_xor(s1, 16); s1 += __shfl_xor(s1, 32);
  w1 += __shfl_xor(w1, 16); w1 += __shfl_xor(w1, 32);
  float mu1 = s1*(1.f/96.f);
  float rs1 = rsqrtf(fmaxf(w1*(1.f/96.f)-mu1*mu1, 0.f) + 1e-5f);
  bf8v fb[3];
  #pragma unroll
  for (int ks = 0; ks < 3; ++ks){
    int k0 = ks*32 + q*8;
    float gv[8], bv[8];
    *(float4*)(gv)   = *(const float4*)(lng + k0);
    *(float4*)(gv+4) = *(const float4*)(lng + k0 + 4);
    *(float4*)(bv)   = *(const float4*)(lnb + k0);
    *(float4*)(bv+4) = *(const float4*)(lnb + k0 + 4);
    float v0[8];
    #pragma unroll
    for (int j = 0; j < 8; ++j)
      v0[j] = (a0v[ks*8+j]-mu1)*rs1*gv[j] + bv[j];
    FragU U0; U0.u = pack8(v0);
    fb[ks] = U0.v;
  }
  __syncthreads();   // Vl visible to half1 epilogue

  {
    f4v aw[6];
    #pragma unroll
    for (int j=0;j<6;++j)
      #pragma unroll
      for (int r=0;r<4;++r) aw[j][r] = 0.f;
    const bf8v* bpw = (const bf8v*)(WiT) + (size_t)l15*12 + q;
    #pragma unroll
    for (int ks = 0; ks < 3; ++ks)
      #pragma unroll
      for (int nf = 0; nf < 6; ++nf){
        bf8v bb = bpw[(half*6+nf)*192 + ks*4];
        aw[nf] = __builtin_amdgcn_mfma_f32_16x16x32_bf16(fb[ks], bb, aw[nf], 0, 0, 0);
      }
    if (half == 0){
      #pragma unroll
      for (int nf=0; nf<6; ++nf)
        #pragma unroll
        for (int r=0; r<4; ++r){
          int m = m0 + q*4 + r;
          int n = nf*16 + l15;
          xin[(size_t)m*96 + n] = f2b(aw[nf][r]);
        }
    } else {
      #pragma unroll
      for (int nf=0; nf<6; ++nf)
        #pragma unroll
        for (int r=0; r<4; ++r){
          int m = m0 + q*4 + r;
          int n = nf*16 + l15;
          float v = aw[nf][r];
          float s = v * sigf(v);
          zsv[(size_t)m*96 + n] = f2b(s * Vl[tl][q*4+r]);
        }
    }
  }
}

// ---------------- fused: Wout GEMM (A = y2*zsv) + gated residual (+ lnLN + Win) --------
template<bool DOLN>
__global__ __launch_bounds__(256) void k_woutln(
    const unsigned short* __restrict__ y2, const unsigned short* __restrict__ WoT,
    const unsigned short* __restrict__ gate,
    const float* __restrict__ lng, const float* __restrict__ lnb,
    const unsigned short* __restrict__ WiT, const float* __restrict__ vis,
    float* __restrict__ tok, unsigned short* __restrict__ xin,
    unsigned short* __restrict__ zsv)
{
  __shared__ float Sl[2][16][100];
  int wid = threadIdx.x >> 6, lane = threadIdx.x & 63;
  int gid = blockIdx.x*4 + wid;
  int tile = gid >> 1, half = gid & 1;
  int tl = wid >> 1;
  int m0 = tile*16;
  int l15 = lane & 15, q = lane >> 4;

  f4v acc[3];
  #pragma unroll
  for (int j=0;j<3;++j)
    #pragma unroll
    for (int r=0;r<4;++r) acc[j][r] = 0.f;
  const bf8v* a0p = (const bf8v*)(y2) + (size_t)(m0 + l15)*12 + q;
  const bf8v* z0p = (const bf8v*)(zsv) + (size_t)(m0 + l15)*12 + q;
  const bf8v* bp  = (const bf8v*)(WoT) + (size_t)l15*12 + q;
  #pragma unroll
  for (int ks = 0; ks < 3; ++ks){
    FragU Ua, Uz; Ua.v = a0p[ks*4]; Uz.v = z0p[ks*4];
    float av[8], zv[8];
    unpack8(Ua.u, av); unpack8(Uz.u, zv);
    float pv[8];
    #pragma unroll
    for (int j = 0; j < 8; ++j) pv[j] = av[j]*zv[j];
    FragU Up; Up.u = pack8(pv);
    bf8v a0 = Up.v;
    #pragma unroll
    for (int nf = 0; nf < 3; ++nf){
      bf8v bb = bp[(half*3+nf)*192 + ks*4];
      acc[nf] = __builtin_amdgcn_mfma_f32_16x16x32_bf16(a0, bb, acc[nf], 0, 0, 0);
    }
  }
  #pragma unroll
  for (int nf=0; nf<3; ++nf)
    #pragma unroll
    for (int r=0; r<4; ++r){
      int m = m0 + q*4 + r;
      int n = (half*3+nf)*16 + l15;
      size_t i = (size_t)m*96 + n;
      float tn = tok[i] + acc[nf][r] * b2f(gate[i]);
      tok[i] = tn;
      if constexpr (DOLN) Sl[tl][q*4+r][n] = tn;
    }

  if constexpr (DOLN){
    __syncthreads();
    int ma0 = m0 + l15;
    float a0v[24];
    float s0=0.f, w0=0.f;
    #pragma unroll
    for (int ks = 0; ks < 3; ++ks){
      int k0 = ks*32 + q*8;
      #pragma unroll
      for (int h = 0; h < 2; ++h){
        float4 va = *(const float4*)(&Sl[tl][l15][k0 + h*4]);
        int o = ks*8 + h*4;
        a0v[o+0]=va.x; a0v[o+1]=va.y; a0v[o+2]=va.z; a0v[o+3]=va.w;
        s0 += (va.x+va.y)+(va.z+va.w);
        w0 += (va.x*va.x+va.y*va.y)+(va.z*va.z+va.w*va.w);
      }
    }
    s0 += __shfl_xor(s0, 16); s0 += __shfl_xor(s0, 32);
    w0 += __shfl_xor(w0, 16); w0 += __shfl_xor(w0, 32);
    float mu0 = s0*(1.f/96.f);
    float rs0 = rsqrtf(fmaxf(w0*(1.f/96.f)-mu0*mu0, 0.f) + 1e-5f);
    bf8v fb[3];
    #pragma unroll
    for (int ks = 0; ks < 3; ++ks){
      int k0 = ks*32 + q*8;
      float gv[8], bv[8];
      *(float4*)(gv)   = *(const float4*)(lng + k0);
      *(float4*)(gv+4) = *(const float4*)(lng + k0 + 4);
      *(float4*)(bv)   = *(const float4*)(lnb + k0);
      *(float4*)(bv+4) = *(const float4*)(lnb + k0 + 4);
      float v0[8];
      #pragma unroll
      for (int j = 0; j < 8; ++j)
        v0[j] = (a0v[ks*8+j]-mu0)*rs0*gv[j] + bv[j];
      FragU U0; U0.u = pack8(v0);
      fb[ks] = U0.v;
    }
    f4v aw[6];
    #pragma unroll
    for (int j=0;j<6;++j)
      #pragma unroll
      for (int r=0;r<4;++r) aw[j][r] = 0.f;
    const bf8v* bpw = (const bf8v*)(WiT) + (size_t)l15*12 + q;
    #pragma unroll
    for (int ks = 0; ks < 3; ++ks)
      #pragma unroll
      for (int nf = 0; nf < 6; ++nf){
        bf8v bb = bpw[(half*6+nf)*192 + ks*4];
        aw[nf] = __builtin_amdgcn_mfma_f32_16x16x32_bf16(fb[ks], bb, aw[nf], 0, 0, 0);
      }
    if (half == 0){
      #pragma unroll
      for (int nf=0; nf<6; ++nf)
        #pragma unroll
        for (int r=0; r<4; ++r){
          int m = m0 + q*4 + r;
          int n = nf*16 + l15;
          xin[(size_t)m*96 + n] = f2b(aw[nf][r]);
        }
    } else {
      #pragma unroll
      for (int nf=0; nf<6; ++nf)
        #pragma unroll
        for (int r=0; r<4; ++r){
          int m = m0 + q*4 + r;
          int n = nf*16 + l15;
          float v = aw[nf][r];
          float sgl = v * sigf(v);
          zsv[(size_t)m*96 + n] = f2b(sgl * vis[m]);
        }
    }
  }
}

// ---------------- fused causal dconv+silu + xproj GEMM; writes dt/xs TRANSPOSED -------
__global__ __launch_bounds__(256) void k_convxp(const unsigned short* __restrict__ xinb,
    const float* __restrict__ cwsplit, const unsigned short* __restrict__ BT,
    const float* __restrict__ bdt, unsigned short* __restrict__ xs_t,
    unsigned short* __restrict__ dt_t, unsigned short* __restrict__ bc)
{
  __shared__ unsigned short xs_l[2][96][16];  // 6144 B
  __shared__ unsigned short dt_l[2][96][16];  // 6144 B
  int wid = threadIdx.x >> 6, lane = threadIdx.x & 63;
  int gid = blockIdx.x*4 + wid;
  int tile = gid >> 1, half = gid & 1;
  int tl = wid >> 1;
  int m0 = tile*16;
  int nf0 = half*4;
  int l15 = lane & 15, q = lane >> 4;
  int ma0 = m0 + l15;
  int t0 = ma0 % 576;
  const float* cw0 = cwsplit;
  const float* cw1 = cwsplit + 96;
  const float* cw2 = cwsplit + 192;

  bf8v fa0[3];
  uint4 z4 = make_uint4(0,0,0,0);
  #pragma unroll
  for (int ks = 0; ks < 3; ++ks){
    int k0 = ks*32 + q*8;
    const unsigned short* r0p = xinb + (size_t)ma0*96 + k0;
    uint4 c0u  = *(const uint4*)(r0p);
    uint4 p10u = (t0 >= 1) ? *(const uint4*)(r0p - 96)  : z4;
    uint4 p20u = (t0 >= 2) ? *(const uint4*)(r0p - 192) : z4;
    float fc0[8], fp10[8], fp20[8];
    unpack8(c0u, fc0); unpack8(p10u, fp10); unpack8(p20u, fp20);
    float w0v[8], w1v[8], w2v[8];
    *(float4*)(w0v)   = *(const float4*)(cw0 + k0);
    *(float4*)(w0v+4) = *(const float4*)(cw0 + k0 + 4);
    *(float4*)(w1v)   = *(const float4*)(cw1 + k0);
    *(float4*)(w1v+4) = *(const float4*)(cw1 + k0 + 4);
    *(float4*)(w2v)   = *(const float4*)(cw2 + k0);
    *(float4*)(w2v+4) = *(const float4*)(cw2 + k0 + 4);
    float xs0[8];
    #pragma unroll
    for (int j = 0; j < 8; ++j){
      float v0 = w2v[j]*fc0[j] + w1v[j]*fp10[j] + w0v[j]*fp20[j];
      xs0[j] = v0 * sigf(v0);
    }
    FragU U0; U0.u = pack8(xs0);
    fa0[ks] = U0.v;
    if (half == 0){
      const unsigned short* us = (const unsigned short*)&U0.u;
      #pragma unroll
      for (int j = 0; j < 8; ++j) xs_l[tl][k0+j][l15] = us[j];
    }
  }

  f4v acc[4];
  #pragma unroll
  for (int j=0;j<4;++j)
    #pragma unroll
    for (int r=0;r<4;++r) acc[j][r] = 0.f;
  const bf8v* bp = (const bf8v*)(BT) + (size_t)l15*12 + q;
  #pragma unroll
  for (int ks = 0; ks < 3; ++ks){
    #pragma unroll
    for (int nf = 0; nf < 4; ++nf){
      bf8v bb = bp[(nf0+nf)*192 + ks*4];
      acc[nf] = __builtin_amdgcn_mfma_f32_16x16x32_bf16(fa0[ks], bb, acc[nf], 0, 0, 0);
    }
  }
  #pragma unroll
  for (int nf=0; nf<4; ++nf)
    #pragma unroll
    for (int r=0; r<4; ++r){
      int m = m0 + q*4 + r;
      int n = (nf0+nf)*16 + l15;
      float v = acc[nf][r];
      if (n < 96){
        float xx = v + bdt[n];
        float sp = (xx > 20.f) ? xx : __logf(1.f + __expf(xx));
        dt_l[tl][n][m - m0] = f2b(sp);
      } else {
        bc[(size_t)m*32 + (n-96)] = f2b(v);
      }
    }
  __syncthreads();

  // write-out: 384 units (xs: 0..191, dt: 192..383); each = one (k, tile) 16-token row
  for (int u = threadIdx.x; u < 384; u += 256){
    int isdt = (u >= 192);
    int v2 = isdt ? (u - 192) : u;
    int tlo = v2 / 96; int k = v2 - tlo*96;
    int mt = (blockIdx.x*2 + tlo)*16;
    int b = mt / 576; int tloc = mt - b*576;
    int row = (b*6 + (k >> 4))*16 + (k & 15);
    const uint4* src = (const uint4*)(isdt ? &dt_l[tlo][k][0] : &xs_l[tlo][k][0]);
    unsigned short* dst = (isdt ? dt_t : xs_t) + (size_t)row*576 + tloc;
    ((uint4*)dst)[0] = src[0];
    ((uint4*)dst)[1] = src[1];
  }
}

// ---------------- selective scan: 36 chunks x 16 tokens, vectorized dt/xs loads -------
// All token-loops FULLY UNROLLED so dts/xss/h are statically indexed (VGPR-resident).
__global__ __launch_bounds__(576) void k_scan(const unsigned short* __restrict__ dt_t,
    const unsigned short* __restrict__ xs_t, const unsigned short* __restrict__ bc,
    const float* __restrict__ Amat, const float* __restrict__ Dw,
    unsigned short* __restrict__ y2)
{
  __shared__ float Ul[36*16*17];   // 39168 B
  __shared__ float Sl[36*16];      // 2304 B
  int b = blockIdx.x / 6; int dg = blockIdx.x - b*6;
  int tid = threadIdx.x;
  int c = tid >> 4; int dl = tid & 15; int d = dg*16 + dl;
  float As[16];
  #pragma unroll
  for (int s = 0; s < 16; s += 4){
    float4 t4 = *(const float4*)(Amat + d*16 + s);
    As[s]=t4.x; As[s+1]=t4.y; As[s+2]=t4.z; As[s+3]=t4.w;
  }
  bool fast = true;
  #pragma unroll
  for (int s = 0; s < 16; ++s)
    fast = fast && (fabsf(As[s] + (float)(s+1)) <= 2e-5f*(float)(s+1));

  // vectorized per-thread chunk loads (32 B each, aligned)
  size_t rowoff = ((size_t)(b*6+dg)*16 + dl)*576 + (size_t)c*16;
  const uint4* dtp = (const uint4*)(dt_t + rowoff);
  const uint4* xsp = (const uint4*)(xs_t + rowoff);
  uint4 du0 = dtp[0], du1 = dtp[1];
  uint4 xu0 = xsp[0], xu1 = xsp[1];
  float dts[16], xss[16];
  unpack8(du0, dts); unpack8(du1, dts+8);
  unpack8(xu0, xss); unpack8(xu1, xss+8);

  float h[16];
  #pragma unroll
  for (int s=0;s<16;++s) h[s]=0.f;
  float sdt = 0.f;
  size_t mbase = (size_t)b*576 + (size_t)c*16;
  if (fast){
    #pragma unroll
    for (int i = 0; i < 16; ++i){
      float dtv = dts[i];
      float dtx = dtv * xss[i];
      const uint4* bp = (const uint4*)(bc + (mbase+i)*32);
      float Bv[16];
      unpack8(bp[0], Bv); unpack8(bp[1], Bv+8);
      sdt += dtv;
      float w1=__expf(-dtv), w2=w1*w1, w3=w2*w1, w4=w2*w2;
      float w5=w4*w1, w6=w4*w2, w7=w4*w3, w8=w4*w4;
      float w9=w8*w1, w10=w8*w2, w11=w8*w3, w12=w8*w4;
      float w13=w8*w5, w14=w8*w6, w15=w8*w7, w16=w8*w8;
      float dA[16]={w1,w2,w3,w4,w5,w6,w7,w8,w9,w10,w11,w12,w13,w14,w15,w16};
      #pragma unroll
      for (int s=0;s<16;++s) h[s] = dA[s]*h[s] + dtx*Bv[s];
    }
  } else {
    #pragma unroll
    for (int i = 0; i < 16; ++i){
      float dtv = dts[i];
      float dtx = dtv * xss[i];
      const uint4* bp = (const uint4*)(bc + (mbase+i)*32);
      float Bv[16];
      unpack8(bp[0], Bv); unpack8(bp[1], Bv+8);
      sdt += dtv;
      #pragma unroll
      for (int s=0;s<16;++s) h[s] = __expf(As[s]*dtv)*h[s] + dtx*Bv[s];
    }
  }
  {
    int base = (c*16 + dl)*17;
    #pragma unroll
    for (int s=0;s<16;++s) Ul[base + s] = h[s];
    Sl[c*16 + dl] = sdt;
  }
  __syncthreads();
  if (tid < 256){
    int dl2 = tid >> 4, s2 = tid & 15;
    float A2 = Amat[(dg*16 + dl2)*16 + s2];
    float hh = 0.f;
    for (int cc = 0; cc < 36; ++cc){
      float u = Ul[(cc*16 + dl2)*17 + s2];
      float ss = Sl[cc*16 + dl2];
      hh = __expf(A2*ss)*hh + u;
      Ul[(cc*16 + dl2)*17 + s2] = hh;
    }
  }
  __syncthreads();
  if (c == 0){
    #pragma unroll
    for (int s=0;s<16;++s) h[s] = 0.f;
  } else {
    int base = ((c-1)*16 + dl)*17;
    #pragma unroll
    for (int s=0;s<16;++s) h[s] = Ul[base + s];
  }
  float Dd = Dw[d];
  if (fast){
    #pragma unroll
    for (int i = 0; i < 16; ++i){
      float dtv = dts[i];
      float xv = xss[i];
      float dtx = dtv * xv;
      const uint4* bp = (const uint4*)(bc + (mbase+i)*32);
      float Bv[16], Cv[16];
      unpack8(bp[0], Bv); unpack8(bp[1], Bv+8);
      unpack8(bp[2], Cv); unpack8(bp[3], Cv+8);
      float w1=__expf(-dtv), w2=w1*w1, w3=w2*w1, w4=w2*w2;
      float w5=w4*w1, w6=w4*w2, w7=w4*w3, w8=w4*w4;
      float w9=w8*w1, w10=w8*w2, w11=w8*w3, w12=w8*w4;
      float w13=w8*w5, w14=w8*w6, w15=w8*w7, w16=w8*w8;
      float dA[16]={w1,w2,w3,w4,w5,w6,w7,w8,w9,w10,w11,w12,w13,w14,w15,w16};
      float p0=0.f,p1=0.f,p2=0.f,p3=0.f;
      #pragma unroll
      for (int s=0;s<16;s+=4){
        h[s+0] = dA[s+0]*h[s+0] + dtx*Bv[s+0]; p0 += h[s+0]*Cv[s+0];
        h[s+1] = dA[s+1]*h[s+1] + dtx*Bv[s+1]; p1 += h[s+1]*Cv[s+1];
        h[s+2] = dA[s+2]*h[s+2] + dtx*Bv[s+2]; p2 += h[s+2]*Cv[s+2];
        h[s+3] = dA[s+3]*h[s+3] + dtx*Bv[s+3]; p3 += h[s+3]*Cv[s+3];
      }
      float y = (p0+p1) + (p2+p3);
      y2[(mbase+i)*96 + d] = f2b(y + Dd*xv);
    }
  } else {
    #pragma unroll
    for (int i = 0; i < 16; ++i){
      float dtv = dts[i];
      float xv = xss[i];
      float dtx = dtv * xv;
      const uint4* bp = (const uint4*)(bc + (mbase+i)*32);
      float Bv[16], Cv[16];
      unpack8(bp[0], Bv); unpack8(bp[1], Bv+8);
      unpack8(bp[2], Cv); unpack8(bp[3], Cv+8);
      float p0=0.f,p1=0.f,p2=0.f,p3=0.f;
      #pragma unroll
      for (int s=0;s<16;s+=4){
        h[s+0] = __expf(As[s+0]*dtv)*h[s+0] + dtx*Bv[s+0]; p0 += h[s+0]*Cv[s+0];
        h[s+1] = __expf(As[s+1]*dtv)*h[s+1] + dtx*Bv[s+1]; p1 += h[s+1]*Cv[s+1];
        h[s+2] = __expf(As[s+2]*dtv)*h[s+2] + dtx*Bv[s+2]; p2 += h[s+2]*Cv[s+2];
        h[s+3] = __expf(As[s+3]*dtv)*h[s+3] + dtx*Bv[s+3]; p3 += h[s+3]*Cv[s+3];
      }
      float y = (p0+p1) + (p2+p3);
      y2[(mbase+i)*96 + d] = f2b(y + Dd*xv);
    }
  }
}

// ---------------- head: depthwise 3x3 + BN + silu + linear heads ----------------
__global__ __launch_bounds__(256) void k_head(const float* __restrict__ tokens,
    const float* __restrict__ hdw, const float* __restrict__ bng,
    const float* __restrict__ bnb, const float* __restrict__ bnm,
    const float* __restrict__ bnv, const float* __restrict__ Wheat,
    const float* __restrict__ bheat, const float* __restrict__ Woff,
    const float* __restrict__ boff, const float* __restrict__ Wsize,
    const float* __restrict__ bsize, float* __restrict__ out)
{
  __shared__ float ft[3*2304];
  __shared__ float act[2304];
  int b = blockIdx.x / 24; int h = blockIdx.x - b*24;
  for (int i = threadIdx.x; i < 3*2304; i += 256){
    int rr = i / 2304; int j = i - rr*2304;
    int hh = h + rr - 1;
    float v = 0.f;
    if (hh >= 0 && hh < 24) v = tokens[((size_t)b*576 + hh*24)*96 + j];
    ft[rr*2304 + j] = v;
  }
  __syncthreads();
  for (int i = threadIdx.x; i < 2304; i += 256){
    int w = i / 96; int cc = i - w*96;
    float g = 0.f;
    #pragma unroll
    for (int dh = 0; dh < 3; ++dh){
      #pragma unroll
      for (int dw = 0; dw < 3; ++dw){
        int ww = w + dw - 1;
        if (ww >= 0 && ww < 24) g += ft[dh*2304 + ww*96 + cc] * hdw[cc*9 + dh*3 + dw];
      }
    }
    float gn = (g - bnm[cc]) * rsqrtf(bnv[cc] + 1e-5f);
    float a = gn * bng[cc] + bnb[cc];
    act[i] = a * sigf(a);
  }
  __syncthreads();
  int tid = threadIdx.x;
  if (tid < 120){
    int o = tid / 24; int w = tid - o*24;
    float s = 0.f;
    for (int cc = 0; cc < 96; ++cc) s += act[w*96 + cc] * Wheat[o*96 + cc];
    s += bheat[o];
    out[(size_t)b*2880 + o*576 + h*24 + w] = s;
  } else if (tid >= 128 && tid < 224){
    int idx = tid - 128; int o2 = idx / 24; int w = idx - o2*24;
    const float* W = (o2 < 2) ? Woff : Wsize;
    int o = o2 & 1;
    float s = 0.f;
    for (int cc = 0; cc < 96; ++cc) s += ft[2304 + w*96 + cc] * W[o*96 + cc];
    s += ((o2 < 2) ? boff : bsize)[o];
    size_t baseo = (o2 < 2) ? (size_t)184320 : (size_t)258048;
    out[baseo + (size_t)b*1152 + o*576 + h*24 + w] = s;
  }
}

// ---------------- host ----------------
extern "C" void kernel_launch(void* const* d_in, const int* in_sizes, int n_in,
                              void* d_out, int out_size, void* d_ws, size_t ws_size,
                              hipStream_t stream)
{
  (void)in_sizes; (void)n_in; (void)out_size;
  const float* x      = (const float*)d_in[0];
  const float* Wpe    = (const float*)d_in[1];
  const float* bpe    = (const float*)d_in[2];
  const float* Wvis   = (const float*)d_in[3];
  const float* bvis   = (const float*)d_in[4];
  const float* dng    = (const float*)d_in[5];
  const float* dnb    = (const float*)d_in[6];
  const float* Wgate  = (const float*)d_in[7];
  const float* bgate  = (const float*)d_in[8];
  const float* lng    = (const float*)d_in[9];
  const float* lnb    = (const float*)d_in[10];
  const float* Win    = (const float*)d_in[11];
  const float* convw  = (const float*)d_in[12];
  const float* Wxproj = (const float*)d_in[13];
  const float* Wdt    = (const float*)d_in[14];
  const float* bdt    = (const float*)d_in[15];
  const float* Alog   = (const float*)d_in[16];
  const float* Dw     = (const float*)d_in[17];
  const float* Wout   = (const float*)d_in[18];
  const float* hddw   = (const float*)d_in[19];
  const float* bng    = (const float*)d_in[20];
  const float* bnb    = (const float*)d_in[21];
  const float* bnm    = (const float*)d_in[22];
  const float* bnv    = (const float*)d_in[23];
  const float* Wheat  = (const float*)d_in[24];
  const float* bheat  = (const float*)d_in[25];
  const float* Woff   = (const float*)d_in[26];
  const float* boff   = (const float*)d_in[27];
  const float* Wsize  = (const float*)d_in[28];
  const float* bsize  = (const float*)d_in[29];
  float* out = (float*)d_out;

  const bool big = ws_size >= (size_t)120324096;
  char* ws = (char*)d_ws;

  size_t o_xlog = 0;
  size_t o_tok  = 56623104;
  size_t o_vis  = 70778880;
  size_t o_wgt  = 70926336;
  size_t o_wit  = 70944768;
  size_t o_wxt  = 70981632;
  size_t o_wot  = 71006208;
  size_t o_amat = 71024640;
  size_t o_wpe  = 71030784;
  size_t o_cw   = 71178240;
  size_t o_gate, o_xin, o_zsv, o_xsb, o_y2, o_dt, o_bc;
  if (big){
    o_gate = 75497472;  o_xin = 82575360;  o_zsv = 89653248;
    o_xsb  = 96731136;  o_y2  = 103809024; o_dt  = 110886912; o_bc = 117964800;
  } else {
    o_bc   = 0;         o_gate = 14155776; o_xsb = 21233664;
    o_y2   = 28311552;  o_xin  = 35389440; o_zsv = 42467328;  o_dt = 49545216;
  }

  unsigned short* xlog  = (unsigned short*)(ws + o_xlog);
  float*          tok   = (float*)(ws + o_tok);
  float*          vis   = (float*)(ws + o_vis);
  unsigned short* WgT   = (unsigned short*)(ws + o_wgt);
  unsigned short* WiT   = (unsigned short*)(ws + o_wit);
  unsigned short* WxT   = (unsigned short*)(ws + o_wxt);
  unsigned short* WoT   = (unsigned short*)(ws + o_wot);
  float*          Amat  = (float*)(ws + o_amat);
  unsigned short* WpeB  = (unsigned short*)(ws + o_wpe);
  float*          cwsp  = (float*)(ws + o_cw);
  unsigned short* gate  = (unsigned short*)(ws + o_gate);
  unsigned short* xinb  = (unsigned short*)(ws + o_xin);
  unsigned short* zsvb  = (unsigned short*)(ws + o_zsv);
  unsigned short* xst   = (unsigned short*)(ws + o_xsb);
  unsigned short* y2    = (unsigned short*)(ws + o_y2);
  unsigned short* dtt   = (unsigned short*)(ws + o_dt);
  unsigned short* bcb   = (unsigned short*)(ws + o_bc);

  k_prep<<<128, 256, 0, stream>>>(Wgate, Win, Wxproj, Wdt, Wout, Alog, Wpe, convw,
                                  WgT, WiT, WxT, WoT, Amat, WpeB, cwsp);
  k_blur<<<9216, 256, 0, stream>>>(x, xlog);
  if (big){
    k_patchfull<<<1152, 256, 0, stream>>>(xlog, WpeB, bpe, dng, dnb, Wvis, bvis,
                                          WgT, bgate, lng, lnb, WiT,
                                          tok, gate, vis, xinb, zsvb);
  } else {
    k_patchln<<<576, 256, 0, stream>>>(xlog, WpeB, bpe, dng, dnb, Wvis, bvis, tok, vis);
    k_lnfull<<<1152, 256, 0, stream>>>(tok, WgT, bgate, lng, lnb, WiT, vis,
                                       gate, xinb, zsvb);
  }

  for (int rep = 0; rep < 4; ++rep){
    k_convxp<<<1152, 256, 0, stream>>>(xinb, cwsp, WxT, bdt, xst, dtt, bcb);
    k_scan<<<384, 576, 0, stream>>>(dtt, xst, bcb, Amat, Dw, y2);
    if (rep < 3)
      k_woutln<true><<<1152, 256, 0, stream>>>(y2, WoT, gate, lng, lnb, WiT, vis,
                                               tok, xinb, zsvb);
    else
      k_woutln<false><<<1152, 256, 0, stream>>>(y2, WoT, gate, lng, lnb, WiT, vis,
                                                tok, xinb, zsvb);
  }

  k_head<<<1536, 256, 0, stream>>>(tok, hddw, bng, bnb, bnm, bnv,
                                   Wheat, bheat, Woff, boff, Wsize, bsize, out);
}

// Round 11
// 655.720 us; speedup vs baseline: 1.8727x; 1.8727x over previous
//
#include <hip/hip_runtime.h>

#define DEVINL __device__ __forceinline__

typedef __attribute__((ext_vector_type(8))) short bf8v;
typedef __attribute__((ext_vector_type(4))) float f4v;

DEVINL float b2f(unsigned short u){ union{unsigned int i; float f;} x; x.i = ((unsigned int)u)<<16; return x.f; }
DEVINL unsigned short f2b(float f){ union{float f; unsigned int i;} x; x.f = f; unsigned int r = x.i + 0x7FFFu + ((x.i>>16)&1u); return (unsigned short)(r>>16); }
DEVINL float sigf(float v){ return 1.f/(1.f + __expf(-v)); }
DEVINL void unpack8(const uint4 u, float* d){
  d[0]=b2f((unsigned short)(u.x)); d[1]=b2f((unsigned short)(u.x>>16));
  d[2]=b2f((unsigned short)(u.y)); d[3]=b2f((unsigned short)(u.y>>16));
  d[4]=b2f((unsigned short)(u.z)); d[5]=b2f((unsigned short)(u.z>>16));
  d[6]=b2f((unsigned short)(u.w)); d[7]=b2f((unsigned short)(u.w>>16));
}
DEVINL uint4 pack8(const float* s){
  uint4 u;
  u.x = (unsigned int)f2b(s[0]) | ((unsigned int)f2b(s[1])<<16);
  u.y = (unsigned int)f2b(s[2]) | ((unsigned int)f2b(s[3])<<16);
  u.z = (unsigned int)f2b(s[4]) | ((unsigned int)f2b(s[5])<<16);
  u.w = (unsigned int)f2b(s[6]) | ((unsigned int)f2b(s[7])<<16);
  return u;
}
union FragU { uint4 u; bf8v v; };

// B=64 IMG=384 PS=16 DM=96 DS=16 DI=96 DT_RANK=6 NREP=4 NCLS=5 HP=24 N=576, M=36864
//
// R11 = R7 proven structure (660.7 us) + zsv-multiply fused into k_woutln
// (twice correctness-proven in R8/R10). Transposed-scan experiment abandoned:
// it spills regardless of unrolling (R8: 107 MB scratch, R10: 325 MB).
// Workspace layout chosen AT RUNTIME from ws_size (defensive).

// ---------------- prep ----------------
#define PREP_STRIDE (128*256)
__global__ __launch_bounds__(256) void k_prep(
    const float* __restrict__ Wgate, const float* __restrict__ Win,
    const float* __restrict__ Wxproj, const float* __restrict__ Wdt,
    const float* __restrict__ Wout, const float* __restrict__ Alog,
    const float* __restrict__ Wpe, const float* __restrict__ convw,
    unsigned short* __restrict__ WgT, unsigned short* __restrict__ WiT,
    unsigned short* __restrict__ WxT, unsigned short* __restrict__ WoT,
    float* __restrict__ Amat, unsigned short* __restrict__ WpeB,
    float* __restrict__ cwsplit)
{
  int gtid = blockIdx.x*256 + threadIdx.x;
  for (int i = gtid; i < 9216; i += PREP_STRIDE){
    int n = i/96, k = i - n*96;
    WgT[n*96+k] = f2b(Wgate[k*96+n]);
    WoT[n*96+k] = f2b(Wout[k*96+n]);
  }
  for (int i = gtid; i < 18432; i += PREP_STRIDE){
    int n = i/96, k = i - n*96;
    WiT[n*96+k] = f2b(Win[k*192+n]);
  }
  for (int i = gtid; i < 12288; i += PREP_STRIDE){
    int n = i/96, k = i - n*96;
    if (n < 96){
      float s = 0.f;
      for (int r = 0; r < 6; ++r) s += Wxproj[k*38+r] * Wdt[r*96+n];
      WxT[n*96+k] = f2b(s);
    } else {
      WxT[n*96+k] = f2b(Wxproj[k*38 + 6 + (n-96)]);
    }
  }
  for (int i = gtid; i < 1536; i += PREP_STRIDE) Amat[i] = -__expf(Alog[i]);
  for (int i = gtid; i < 73728; i += PREP_STRIDE) WpeB[i] = f2b(Wpe[i]);
  for (int i = gtid; i < 96; i += PREP_STRIDE){
    cwsplit[i]       = convw[i*3+0];
    cwsplit[96+i]    = convw[i*3+1];
    cwsplit[192+i]   = convw[i*3+2];
  }
}

// ---------------- K1: 5x5 box blur + log1p diff -> xlog (bf16) ----------------
// R1-variant (measured best: 66 us): bf16 staging + separate vt phase, 8-row tiles.
__global__ __launch_bounds__(256) void k_blur(const float* __restrict__ x,
                                              unsigned short* __restrict__ xlog)
{
  __shared__ unsigned short xt[12*384];  // raw rows y0-2..y0+9, bf16 (9216 B)
  __shared__ float vt[8*392];            // vertical 5-sums, padded (12544 B)
  int bid = blockIdx.x;                  // 64*3*48
  int tile = bid % 48; int bc = bid / 48; int c = bc % 3; int b = bc / 3;
  const float* xin = x + (size_t)(b*3 + c) * 147456;
  unsigned short* xout = xlog + (size_t)(b*3 + c) * 147456;
  int y0 = tile * 8;
  int tid = threadIdx.x;

  #pragma unroll
  for (int k = 0; k < 5; ++k){
    int idx = tid + k*256;
    if (idx < 1152){
      int r = idx / 96; int c4 = idx - r*96;
      int gy = y0 - 2 + r;
      float4 v = make_float4(0.f,0.f,0.f,0.f);
      if (gy >= 0 && gy < 384) v = *(const float4*)(xin + gy*384 + c4*4);
      ushort4 o; o.x=f2b(v.x); o.y=f2b(v.y); o.z=f2b(v.z); o.w=f2b(v.w);
      *(ushort4*)(xt + r*384 + c4*4) = o;
    }
  }
  if (tid < 64){
    int r = tid >> 3; int j = tid & 7;
    vt[r*392 + ((j < 4) ? j : (384 + j))] = 0.f;
  }
  __syncthreads();

  #pragma unroll
  for (int k = 0; k < 2; ++k){
    int unit = tid + k*256;
    if (unit < 384){
      int r = unit / 48; int c8 = unit - r*48;
      const unsigned short* base = xt + r*384 + c8*8;
      float acc[8]; float t[8];
      uint4 u0 = *(const uint4*)(base);
      unpack8(u0, acc);
      #pragma unroll
      for (int i = 1; i < 5; ++i){
        uint4 u = *(const uint4*)(base + i*384);
        unpack8(u, t);
        #pragma unroll
        for (int j = 0; j < 8; ++j) acc[j] += t[j];
      }
      float* vrow = vt + r*392 + 4 + c8*8;
      *(float4*)(vrow)   = make_float4(acc[0],acc[1],acc[2],acc[3]);
      *(float4*)(vrow+4) = make_float4(acc[4],acc[5],acc[6],acc[7]);
    }
  }
  __syncthreads();

  #pragma unroll
  for (int k = 0; k < 3; ++k){
    int unit = tid + k*256;
    int r = unit / 96; int c4 = unit - r*96;
    int base = r*392 + 4 + c4*4;
    float f[12];
    *(float4*)(f)   = *(const float4*)(vt + base - 4);
    *(float4*)(f+4) = *(const float4*)(vt + base);
    *(float4*)(f+8) = *(const float4*)(vt + base + 4);
    ushort4 xr = *(const ushort4*)(xt + (r+2)*384 + c4*4);
    const unsigned short* xrp = &xr.x;
    ushort4 o;
    unsigned short* op = &o.x;
    #pragma unroll
    for (int j = 0; j < 4; ++j){
      float s = f[2+j] + f[3+j] + f[4+j] + f[5+j] + f[6+j];
      float L = fmaxf(s * 0.04f, 0.f);
      float xv = fmaxf(b2f(xrp[j]), 0.f);
      op[j] = f2b(__logf(1.f + xv) - __logf(1.f + L));
    }
    *(ushort4*)(xout + (y0+r)*384 + c4*4) = o;
  }
}

// ---------------- K2a (fallback): patch embed + bias + dn-LN + vis ----------------
__global__ __launch_bounds__(256) void k_patchln(
    const unsigned short* __restrict__ xlog, const unsigned short* __restrict__ WpeB,
    const float* __restrict__ bpe, const float* __restrict__ dng,
    const float* __restrict__ dnb, const float* __restrict__ Wvis,
    const float* __restrict__ bvis, float* __restrict__ tok, float* __restrict__ vis)
{
  int wid = threadIdx.x >> 6, lane = threadIdx.x & 63;
  int m0 = (blockIdx.x*4 + wid)*16;
  int l15 = lane & 15, q = lane >> 4;
  int ma0 = m0 + l15;
  int b0 = ma0/576; int r0 = ma0 - b0*576; int hp0 = r0/24; int wp0 = r0 - hp0*24;
  size_t base0 = (size_t)b0*442368 + (size_t)hp0*6144 + (size_t)wp0*16;
  f4v acc[6];
  #pragma unroll
  for (int j=0;j<6;++j)
    #pragma unroll
    for (int r=0;r<4;++r) acc[j][r] = 0.f;
  for (int ks = 0; ks < 24; ++ks){
    int k0 = ks*32 + q*8;
    int c  = k0 >> 8;
    int ph = (k0 >> 4) & 15;
    int pw = k0 & 15;
    size_t off = (size_t)c*147456 + (size_t)ph*384 + pw;
    bf8v a0 = *(const bf8v*)(xlog + base0 + off);
    #pragma unroll
    for (int nf = 0; nf < 6; ++nf){
      bf8v bb = *(const bf8v*)(WpeB + (size_t)(nf*16 + l15)*768 + k0);
      acc[nf] = __builtin_amdgcn_mfma_f32_16x16x32_bf16(a0, bb, acc[nf], 0, 0, 0);
    }
  }
  float v[6][4];
  float s[4], w[4], vd[4];
  #pragma unroll
  for (int r=0;r<4;++r){ s[r]=0.f; w[r]=0.f; vd[r]=0.f; }
  #pragma unroll
  for (int nf=0; nf<6; ++nf){
    int n = nf*16 + l15;
    float bp = bpe[n];
    float wv = Wvis[n];
    #pragma unroll
    for (int r=0;r<4;++r){
      float t = acc[nf][r] + bp;
      v[nf][r] = t;
      s[r] += t; w[r] += t*t; vd[r] += t*wv;
    }
  }
  #pragma unroll
  for (int off=1; off<16; off<<=1){
    #pragma unroll
    for (int r=0;r<4;++r){
      s[r]  += __shfl_xor(s[r],  off);
      w[r]  += __shfl_xor(w[r],  off);
      vd[r] += __shfl_xor(vd[r], off);
    }
  }
  float mu[4], rs[4];
  #pragma unroll
  for (int r=0;r<4;++r){
    mu[r] = s[r]*(1.f/96.f);
    rs[r] = rsqrtf(fmaxf(w[r]*(1.f/96.f)-mu[r]*mu[r], 0.f) + 1e-5f);
  }
  if (l15 == 0){
    #pragma unroll
    for (int r=0;r<4;++r) vis[m0 + q*4 + r] = sigf(vd[r] + bvis[0]);
  }
  #pragma unroll
  for (int nf=0; nf<6; ++nf){
    int n = nf*16 + l15;
    float g = dng[n], bb = dnb[n];
    #pragma unroll
    for (int r=0;r<4;++r)
      tok[(size_t)(m0 + q*4 + r)*96 + n] = (v[nf][r]-mu[r])*rs[r]*g + bb;
  }
}

// ---------------- K2b (fallback): gate GEMM + lnLN + Win GEMM (N-split x2) ------------
__global__ __launch_bounds__(256) void k_lnfull(const float* __restrict__ tokp,
    const unsigned short* __restrict__ WgT, const float* __restrict__ bg,
    const float* __restrict__ lng, const float* __restrict__ lnb,
    const unsigned short* __restrict__ WiT, const float* __restrict__ vis,
    unsigned short* __restrict__ gate, unsigned short* __restrict__ xin,
    unsigned short* __restrict__ zsv)
{
  int wid = threadIdx.x >> 6, lane = threadIdx.x & 63;
  int gid = blockIdx.x*4 + wid;
  int tile = gid >> 1, half = gid & 1;
  int m0 = tile*16;
  int l15 = lane & 15, q = lane >> 4;
  int ma0 = m0 + l15;
  float a0v[24];
  float s1=0.f, w1=0.f;
  bf8v fa[3];
  #pragma unroll
  for (int ks = 0; ks < 3; ++ks){
    int k0 = ks*32 + q*8;
    float v0[8];
    #pragma unroll
    for (int h = 0; h < 2; ++h){
      float4 va = *(const float4*)(tokp + (size_t)ma0*96 + k0 + h*4);
      int o = ks*8 + h*4;
      a0v[o+0]=va.x; a0v[o+1]=va.y; a0v[o+2]=va.z; a0v[o+3]=va.w;
      v0[h*4+0]=va.x; v0[h*4+1]=va.y; v0[h*4+2]=va.z; v0[h*4+3]=va.w;
      s1 += (va.x+va.y)+(va.z+va.w);
      w1 += (va.x*va.x+va.y*va.y)+(va.z*va.z+va.w*va.w);
    }
    FragU U0; U0.u = pack8(v0);
    fa[ks] = U0.v;
  }
  s1 += __shfl_xor(s1, 16); s1 += __shfl_xor(s1, 32);
  w1 += __shfl_xor(w1, 16); w1 += __shfl_xor(w1, 32);
  float mu1 = s1*(1.f/96.f);
  float rs1 = rsqrtf(fmaxf(w1*(1.f/96.f)-mu1*mu1, 0.f) + 1e-5f);
  bf8v fb[3];
  #pragma unroll
  for (int ks = 0; ks < 3; ++ks){
    int k0 = ks*32 + q*8;
    float gv[8], bv[8];
    *(float4*)(gv)   = *(const float4*)(lng + k0);
    *(float4*)(gv+4) = *(const float4*)(lng + k0 + 4);
    *(float4*)(bv)   = *(const float4*)(lnb + k0);
    *(float4*)(bv+4) = *(const float4*)(lnb + k0 + 4);
    float v0[8];
    #pragma unroll
    for (int j = 0; j < 8; ++j)
      v0[j] = (a0v[ks*8+j]-mu1)*rs1*gv[j] + bv[j];
    FragU U0; U0.u = pack8(v0);
    fb[ks] = U0.v;
  }
  {
    f4v ag[3];
    #pragma unroll
    for (int j=0;j<3;++j)
      #pragma unroll
      for (int r=0;r<4;++r) ag[j][r] = 0.f;
    const bf8v* bpg = (const bf8v*)(WgT) + (size_t)l15*12 + q;
    #pragma unroll
    for (int ks = 0; ks < 3; ++ks)
      #pragma unroll
      for (int nf = 0; nf < 3; ++nf){
        bf8v bb = bpg[(half*3+nf)*192 + ks*4];
        ag[nf] = __builtin_amdgcn_mfma_f32_16x16x32_bf16(fa[ks], bb, ag[nf], 0, 0, 0);
      }
    #pragma unroll
    for (int nf=0; nf<3; ++nf)
      #pragma unroll
      for (int r=0; r<4; ++r){
        int m = m0 + q*4 + r;
        int n = (half*3+nf)*16 + l15;
        gate[(size_t)m*96 + n] = f2b(sigf(ag[nf][r] + bg[n]));
      }
  }
  {
    f4v aw[6];
    #pragma unroll
    for (int j=0;j<6;++j)
      #pragma unroll
      for (int r=0;r<4;++r) aw[j][r] = 0.f;
    const bf8v* bpw = (const bf8v*)(WiT) + (size_t)l15*12 + q;
    #pragma unroll
    for (int ks = 0; ks < 3; ++ks)
      #pragma unroll
      for (int nf = 0; nf < 6; ++nf){
        bf8v bb = bpw[(half*6+nf)*192 + ks*4];
        aw[nf] = __builtin_amdgcn_mfma_f32_16x16x32_bf16(fb[ks], bb, aw[nf], 0, 0, 0);
      }
    if (half == 0){
      #pragma unroll
      for (int nf=0; nf<6; ++nf)
        #pragma unroll
        for (int r=0; r<4; ++r){
          int m = m0 + q*4 + r;
          int n = nf*16 + l15;
          xin[(size_t)m*96 + n] = f2b(aw[nf][r]);
        }
    } else {
      #pragma unroll
      for (int nf=0; nf<6; ++nf)
        #pragma unroll
        for (int r=0; r<4; ++r){
          int m = m0 + q*4 + r;
          int n = nf*16 + l15;
          float v = aw[nf][r];
          float sgl = v * sigf(v);
          zsv[(size_t)m*96 + n] = f2b(sgl * vis[m]);
        }
    }
  }
}

// ---------------- K2 (big ws): patch + dnLN + vis + gate GEMM + lnLN + Win GEMM -------
__global__ __launch_bounds__(256) void k_patchfull(
    const unsigned short* __restrict__ xlog, const unsigned short* __restrict__ WpeB,
    const float* __restrict__ bpe,
    const float* __restrict__ dng, const float* __restrict__ dnb,
    const float* __restrict__ Wvis, const float* __restrict__ bvis,
    const unsigned short* __restrict__ WgT, const float* __restrict__ bg,
    const float* __restrict__ lng, const float* __restrict__ lnb,
    const unsigned short* __restrict__ WiT,
    float* __restrict__ tok, unsigned short* __restrict__ gate,
    float* __restrict__ vis, unsigned short* __restrict__ xin,
    unsigned short* __restrict__ zsv)
{
  __shared__ float Sl[2][16][100];
  __shared__ float Vl[2][16];
  int wid = threadIdx.x >> 6, lane = threadIdx.x & 63;
  int gid = blockIdx.x*4 + wid;
  int tile = gid >> 1, half = gid & 1;
  int tl = wid >> 1;
  int m0 = tile*16;
  int l15 = lane & 15, q = lane >> 4;
  int ma0 = m0 + l15;

  {
    int b0 = ma0/576; int r0 = ma0 - b0*576; int hp0 = r0/24; int wp0 = r0 - hp0*24;
    size_t base0 = (size_t)b0*442368 + (size_t)hp0*6144 + (size_t)wp0*16;
    f4v acc[3];
    #pragma unroll
    for (int j=0;j<3;++j)
      #pragma unroll
      for (int r=0;r<4;++r) acc[j][r] = 0.f;
    for (int ks = 0; ks < 24; ++ks){
      int k0 = ks*32 + q*8;
      int c  = k0 >> 8;
      int ph = (k0 >> 4) & 15;
      int pw = k0 & 15;
      size_t off = (size_t)c*147456 + (size_t)ph*384 + pw;
      bf8v a0 = *(const bf8v*)(xlog + base0 + off);
      #pragma unroll
      for (int nf = 0; nf < 3; ++nf){
        bf8v bb = *(const bf8v*)(WpeB + (size_t)((half*3+nf)*16 + l15)*768 + k0);
        acc[nf] = __builtin_amdgcn_mfma_f32_16x16x32_bf16(a0, bb, acc[nf], 0, 0, 0);
      }
    }
    #pragma unroll
    for (int nf=0; nf<3; ++nf)
      #pragma unroll
      for (int r=0; r<4; ++r){
        int n = (half*3+nf)*16 + l15;
        Sl[tl][q*4+r][n] = acc[nf][r] + bpe[n];
      }
  }
  __syncthreads();

  float a0v[24];
  float s0=0.f, w0=0.f, vd=0.f;
  #pragma unroll
  for (int ks = 0; ks < 3; ++ks){
    int k0 = ks*32 + q*8;
    #pragma unroll
    for (int h = 0; h < 2; ++h){
      float4 va = *(const float4*)(&Sl[tl][l15][k0 + h*4]);
      float4 wv = *(const float4*)(Wvis + k0 + h*4);
      int o = ks*8 + h*4;
      a0v[o+0]=va.x; a0v[o+1]=va.y; a0v[o+2]=va.z; a0v[o+3]=va.w;
      s0 += (va.x+va.y)+(va.z+va.w);
      w0 += (va.x*va.x+va.y*va.y)+(va.z*va.z+va.w*va.w);
      vd += (va.x*wv.x+va.y*wv.y)+(va.z*wv.z+va.w*wv.w);
    }
  }
  s0 += __shfl_xor(s0, 16); s0 += __shfl_xor(s0, 32);
  w0 += __shfl_xor(w0, 16); w0 += __shfl_xor(w0, 32);
  vd += __shfl_xor(vd, 16); vd += __shfl_xor(vd, 32);
  float mu0 = s0*(1.f/96.f);
  float rs0 = rsqrtf(fmaxf(w0*(1.f/96.f)-mu0*mu0, 0.f) + 1e-5f);
  if (half == 0 && q == 0){
    float vv = sigf(vd + bvis[0]);
    vis[ma0] = vv;
    Vl[tl][l15] = vv;
  }

  bf8v fa[3];
  float s1=0.f, w1=0.f;
  #pragma unroll
  for (int ks = 0; ks < 3; ++ks){
    int k0 = ks*32 + q*8;
    float gv[8], bv[8];
    *(float4*)(gv)   = *(const float4*)(dng + k0);
    *(float4*)(gv+4) = *(const float4*)(dng + k0 + 4);
    *(float4*)(bv)   = *(const float4*)(dnb + k0);
    *(float4*)(bv+4) = *(const float4*)(dnb + k0 + 4);
    float v0[8];
    #pragma unroll
    for (int j = 0; j < 8; ++j){
      float v = (a0v[ks*8+j]-mu0)*rs0*gv[j] + bv[j];
      v0[j] = v;
      a0v[ks*8+j] = v;
      s1 += v; w1 += v*v;
    }
    if (half == 0){
      *(float4*)(tok + (size_t)ma0*96 + k0)     = make_float4(v0[0],v0[1],v0[2],v0[3]);
      *(float4*)(tok + (size_t)ma0*96 + k0 + 4) = make_float4(v0[4],v0[5],v0[6],v0[7]);
    }
    FragU U0; U0.u = pack8(v0);
    fa[ks] = U0.v;
  }

  {
    f4v ag[3];
    #pragma unroll
    for (int j=0;j<3;++j)
      #pragma unroll
      for (int r=0;r<4;++r) ag[j][r] = 0.f;
    const bf8v* bpg = (const bf8v*)(WgT) + (size_t)l15*12 + q;
    #pragma unroll
    for (int ks = 0; ks < 3; ++ks)
      #pragma unroll
      for (int nf = 0; nf < 3; ++nf){
        bf8v bb = bpg[(half*3+nf)*192 + ks*4];
        ag[nf] = __builtin_amdgcn_mfma_f32_16x16x32_bf16(fa[ks], bb, ag[nf], 0, 0, 0);
      }
    #pragma unroll
    for (int nf=0; nf<3; ++nf)
      #pragma unroll
      for (int r=0; r<4; ++r){
        int m = m0 + q*4 + r;
        int n = (half*3+nf)*16 + l15;
        gate[(size_t)m*96 + n] = f2b(sigf(ag[nf][r] + bg[n]));
      }
  }

  s1 += __shfl_xor(s1, 16); s1 += __shfl_xor(s1, 32);
  w1 += __shfl_xor(w1, 16); w1 += __shfl_xor(w1, 32);
  float mu1 = s1*(1.f/96.f);
  float rs1 = rsqrtf(fmaxf(w1*(1.f/96.f)-mu1*mu1, 0.f) + 1e-5f);
  bf8v fb[3];
  #pragma unroll
  for (int ks = 0; ks < 3; ++ks){
    int k0 = ks*32 + q*8;
    float gv[8], bv[8];
    *(float4*)(gv)   = *(const float4*)(lng + k0);
    *(float4*)(gv+4) = *(const float4*)(lng + k0 + 4);
    *(float4*)(bv)   = *(const float4*)(lnb + k0);
    *(float4*)(bv+4) = *(const float4*)(lnb + k0 + 4);
    float v0[8];
    #pragma unroll
    for (int j = 0; j < 8; ++j)
      v0[j] = (a0v[ks*8+j]-mu1)*rs1*gv[j] + bv[j];
    FragU U0; U0.u = pack8(v0);
    fb[ks] = U0.v;
  }
  __syncthreads();   // Vl visible to half1 epilogue

  {
    f4v aw[6];
    #pragma unroll
    for (int j=0;j<6;++j)
      #pragma unroll
      for (int r=0;r<4;++r) aw[j][r] = 0.f;
    const bf8v* bpw = (const bf8v*)(WiT) + (size_t)l15*12 + q;
    #pragma unroll
    for (int ks = 0; ks < 3; ++ks)
      #pragma unroll
      for (int nf = 0; nf < 6; ++nf){
        bf8v bb = bpw[(half*6+nf)*192 + ks*4];
        aw[nf] = __builtin_amdgcn_mfma_f32_16x16x32_bf16(fb[ks], bb, aw[nf], 0, 0, 0);
      }
    if (half == 0){
      #pragma unroll
      for (int nf=0; nf<6; ++nf)
        #pragma unroll
        for (int r=0; r<4; ++r){
          int m = m0 + q*4 + r;
          int n = nf*16 + l15;
          xin[(size_t)m*96 + n] = f2b(aw[nf][r]);
        }
    } else {
      #pragma unroll
      for (int nf=0; nf<6; ++nf)
        #pragma unroll
        for (int r=0; r<4; ++r){
          int m = m0 + q*4 + r;
          int n = nf*16 + l15;
          float v = aw[nf][r];
          float s = v * sigf(v);
          zsv[(size_t)m*96 + n] = f2b(s * Vl[tl][q*4+r]);
        }
    }
  }
}

// ---------------- fused: Wout GEMM (A = y2*zsv) + gated residual (+ lnLN + Win) --------
template<bool DOLN>
__global__ __launch_bounds__(256) void k_woutln(
    const unsigned short* __restrict__ y2, const unsigned short* __restrict__ WoT,
    const unsigned short* __restrict__ gate,
    const float* __restrict__ lng, const float* __restrict__ lnb,
    const unsigned short* __restrict__ WiT, const float* __restrict__ vis,
    float* __restrict__ tok, unsigned short* __restrict__ xin,
    unsigned short* __restrict__ zsv)
{
  __shared__ float Sl[2][16][100];
  int wid = threadIdx.x >> 6, lane = threadIdx.x & 63;
  int gid = blockIdx.x*4 + wid;
  int tile = gid >> 1, half = gid & 1;
  int tl = wid >> 1;
  int m0 = tile*16;
  int l15 = lane & 15, q = lane >> 4;

  f4v acc[3];
  #pragma unroll
  for (int j=0;j<3;++j)
    #pragma unroll
    for (int r=0;r<4;++r) acc[j][r] = 0.f;
  const bf8v* a0p = (const bf8v*)(y2) + (size_t)(m0 + l15)*12 + q;
  const bf8v* z0p = (const bf8v*)(zsv) + (size_t)(m0 + l15)*12 + q;
  const bf8v* bp  = (const bf8v*)(WoT) + (size_t)l15*12 + q;
  #pragma unroll
  for (int ks = 0; ks < 3; ++ks){
    FragU Ua, Uz; Ua.v = a0p[ks*4]; Uz.v = z0p[ks*4];
    float av[8], zv[8];
    unpack8(Ua.u, av); unpack8(Uz.u, zv);
    float pv[8];
    #pragma unroll
    for (int j = 0; j < 8; ++j) pv[j] = av[j]*zv[j];
    FragU Up; Up.u = pack8(pv);
    bf8v a0 = Up.v;
    #pragma unroll
    for (int nf = 0; nf < 3; ++nf){
      bf8v bb = bp[(half*3+nf)*192 + ks*4];
      acc[nf] = __builtin_amdgcn_mfma_f32_16x16x32_bf16(a0, bb, acc[nf], 0, 0, 0);
    }
  }
  #pragma unroll
  for (int nf=0; nf<3; ++nf)
    #pragma unroll
    for (int r=0; r<4; ++r){
      int m = m0 + q*4 + r;
      int n = (half*3+nf)*16 + l15;
      size_t i = (size_t)m*96 + n;
      float tn = tok[i] + acc[nf][r] * b2f(gate[i]);
      tok[i] = tn;
      if constexpr (DOLN) Sl[tl][q*4+r][n] = tn;
    }

  if constexpr (DOLN){
    __syncthreads();
    int ma0 = m0 + l15;
    float a0v[24];
    float s0=0.f, w0=0.f;
    #pragma unroll
    for (int ks = 0; ks < 3; ++ks){
      int k0 = ks*32 + q*8;
      #pragma unroll
      for (int h = 0; h < 2; ++h){
        float4 va = *(const float4*)(&Sl[tl][l15][k0 + h*4]);
        int o = ks*8 + h*4;
        a0v[o+0]=va.x; a0v[o+1]=va.y; a0v[o+2]=va.z; a0v[o+3]=va.w;
        s0 += (va.x+va.y)+(va.z+va.w);
        w0 += (va.x*va.x+va.y*va.y)+(va.z*va.z+va.w*va.w);
      }
    }
    s0 += __shfl_xor(s0, 16); s0 += __shfl_xor(s0, 32);
    w0 += __shfl_xor(w0, 16); w0 += __shfl_xor(w0, 32);
    float mu0 = s0*(1.f/96.f);
    float rs0 = rsqrtf(fmaxf(w0*(1.f/96.f)-mu0*mu0, 0.f) + 1e-5f);
    bf8v fb[3];
    #pragma unroll
    for (int ks = 0; ks < 3; ++ks){
      int k0 = ks*32 + q*8;
      float gv[8], bv[8];
      *(float4*)(gv)   = *(const float4*)(lng + k0);
      *(float4*)(gv+4) = *(const float4*)(lng + k0 + 4);
      *(float4*)(bv)   = *(const float4*)(lnb + k0);
      *(float4*)(bv+4) = *(const float4*)(lnb + k0 + 4);
      float v0[8];
      #pragma unroll
      for (int j = 0; j < 8; ++j)
        v0[j] = (a0v[ks*8+j]-mu0)*rs0*gv[j] + bv[j];
      FragU U0; U0.u = pack8(v0);
      fb[ks] = U0.v;
    }
    f4v aw[6];
    #pragma unroll
    for (int j=0;j<6;++j)
      #pragma unroll
      for (int r=0;r<4;++r) aw[j][r] = 0.f;
    const bf8v* bpw = (const bf8v*)(WiT) + (size_t)l15*12 + q;
    #pragma unroll
    for (int ks = 0; ks < 3; ++ks)
      #pragma unroll
      for (int nf = 0; nf < 6; ++nf){
        bf8v bb = bpw[(half*6+nf)*192 + ks*4];
        aw[nf] = __builtin_amdgcn_mfma_f32_16x16x32_bf16(fb[ks], bb, aw[nf], 0, 0, 0);
      }
    if (half == 0){
      #pragma unroll
      for (int nf=0; nf<6; ++nf)
        #pragma unroll
        for (int r=0; r<4; ++r){
          int m = m0 + q*4 + r;
          int n = nf*16 + l15;
          xin[(size_t)m*96 + n] = f2b(aw[nf][r]);
        }
    } else {
      #pragma unroll
      for (int nf=0; nf<6; ++nf)
        #pragma unroll
        for (int r=0; r<4; ++r){
          int m = m0 + q*4 + r;
          int n = nf*16 + l15;
          float v = aw[nf][r];
          float sgl = v * sigf(v);
          zsv[(size_t)m*96 + n] = f2b(sgl * vis[m]);
        }
    }
  }
}

// ---------------- fused causal dconv+silu + xproj GEMM (N-split x2, R7 form) ----------
__global__ __launch_bounds__(256) void k_convxp(const unsigned short* __restrict__ xinb,
    const float* __restrict__ cwsplit, const unsigned short* __restrict__ BT,
    const float* __restrict__ bdt, unsigned short* __restrict__ xsb,
    unsigned short* __restrict__ dt, unsigned short* __restrict__ bc)
{
  int wid = threadIdx.x >> 6, lane = threadIdx.x & 63;
  int gid = blockIdx.x*4 + wid;
  int tile = gid >> 1, half = gid & 1;
  int m0 = tile*16;
  int nf0 = half*4;
  int l15 = lane & 15, q = lane >> 4;
  int ma0 = m0 + l15;
  int t0 = ma0 % 576;
  const float* cw0 = cwsplit;
  const float* cw1 = cwsplit + 96;
  const float* cw2 = cwsplit + 192;

  bf8v fa0[3];
  uint4 z4 = make_uint4(0,0,0,0);
  #pragma unroll
  for (int ks = 0; ks < 3; ++ks){
    int k0 = ks*32 + q*8;
    const unsigned short* r0p = xinb + (size_t)ma0*96 + k0;
    uint4 c0u  = *(const uint4*)(r0p);
    uint4 p10u = (t0 >= 1) ? *(const uint4*)(r0p - 96)  : z4;
    uint4 p20u = (t0 >= 2) ? *(const uint4*)(r0p - 192) : z4;
    float fc0[8], fp10[8], fp20[8];
    unpack8(c0u, fc0); unpack8(p10u, fp10); unpack8(p20u, fp20);
    float w0v[8], w1v[8], w2v[8];
    *(float4*)(w0v)   = *(const float4*)(cw0 + k0);
    *(float4*)(w0v+4) = *(const float4*)(cw0 + k0 + 4);
    *(float4*)(w1v)   = *(const float4*)(cw1 + k0);
    *(float4*)(w1v+4) = *(const float4*)(cw1 + k0 + 4);
    *(float4*)(w2v)   = *(const float4*)(cw2 + k0);
    *(float4*)(w2v+4) = *(const float4*)(cw2 + k0 + 4);
    float xs0[8];
    #pragma unroll
    for (int j = 0; j < 8; ++j){
      float v0 = w2v[j]*fc0[j] + w1v[j]*fp10[j] + w0v[j]*fp20[j];
      xs0[j] = v0 * sigf(v0);
    }
    FragU U0; U0.u = pack8(xs0);
    fa0[ks] = U0.v;
    if (half == 0) *(uint4*)(xsb + (size_t)ma0*96 + k0) = U0.u;
  }

  f4v acc[4];
  #pragma unroll
  for (int j=0;j<4;++j)
    #pragma unroll
    for (int r=0;r<4;++r) acc[j][r] = 0.f;
  const bf8v* bp = (const bf8v*)(BT) + (size_t)l15*12 + q;
  #pragma unroll
  for (int ks = 0; ks < 3; ++ks){
    #pragma unroll
    for (int nf = 0; nf < 4; ++nf){
      bf8v bb = bp[(nf0+nf)*192 + ks*4];
      acc[nf] = __builtin_amdgcn_mfma_f32_16x16x32_bf16(fa0[ks], bb, acc[nf], 0, 0, 0);
    }
  }
  #pragma unroll
  for (int nf=0; nf<4; ++nf)
    #pragma unroll
    for (int r=0; r<4; ++r){
      int m = m0 + q*4 + r;
      int n = (nf0+nf)*16 + l15;
      float v = acc[nf][r];
      if (n < 96){
        float xx = v + bdt[n];
        float sp = (xx > 20.f) ? xx : __logf(1.f + __expf(xx));
        dt[(size_t)m*96 + n] = f2b(sp);
      } else {
        bc[(size_t)m*32 + (n-96)] = f2b(v);
      }
    }
}

// ---------------- selective scan (R7 form, 32 chunks x 18 tokens, no zsv) -------------
__global__ __launch_bounds__(512) void k_scan(const unsigned short* __restrict__ dt,
    const unsigned short* __restrict__ xsb, const unsigned short* __restrict__ bc,
    const float* __restrict__ Amat, const float* __restrict__ Dw,
    unsigned short* __restrict__ y2)
{
  __shared__ float Ul[32*16*17];
  __shared__ float Sl[32*16];
  int b = blockIdx.x / 6; int dg = blockIdx.x - b*6;
  int tid = threadIdx.x;
  int c = tid >> 4; int dl = tid & 15; int d = dg*16 + dl;
  float As[16];
  #pragma unroll
  for (int s = 0; s < 16; s += 4){
    float4 t4 = *(const float4*)(Amat + d*16 + s);
    As[s]=t4.x; As[s+1]=t4.y; As[s+2]=t4.z; As[s+3]=t4.w;
  }
  bool fast = true;
  #pragma unroll
  for (int s = 0; s < 16; ++s)
    fast = fast && (fabsf(As[s] + (float)(s+1)) <= 2e-5f*(float)(s+1));

  float h[16];
  #pragma unroll
  for (int s=0;s<16;++s) h[s]=0.f;
  float sdt = 0.f;
  int tbase = b*576 + c*18;
  if (fast){
    for (int i = 0; i < 18; ++i){
      size_t m = (size_t)(tbase + i);
      float dtv = b2f(dt[m*96 + d]);
      float dtx = dtv * b2f(xsb[m*96 + d]);
      const uint4* bp = (const uint4*)(bc + m*32);
      float Bv[16];
      unpack8(bp[0], Bv); unpack8(bp[1], Bv+8);
      sdt += dtv;
      float w1=__expf(-dtv), w2=w1*w1, w3=w2*w1, w4=w2*w2;
      float w5=w4*w1, w6=w4*w2, w7=w4*w3, w8=w4*w4;
      float w9=w8*w1, w10=w8*w2, w11=w8*w3, w12=w8*w4;
      float w13=w8*w5, w14=w8*w6, w15=w8*w7, w16=w8*w8;
      float dA[16]={w1,w2,w3,w4,w5,w6,w7,w8,w9,w10,w11,w12,w13,w14,w15,w16};
      #pragma unroll
      for (int s=0;s<16;++s) h[s] = dA[s]*h[s] + dtx*Bv[s];
    }
  } else {
    for (int i = 0; i < 18; ++i){
      size_t m = (size_t)(tbase + i);
      float dtv = b2f(dt[m*96 + d]);
      float dtx = dtv * b2f(xsb[m*96 + d]);
      const uint4* bp = (const uint4*)(bc + m*32);
      float Bv[16];
      unpack8(bp[0], Bv); unpack8(bp[1], Bv+8);
      sdt += dtv;
      #pragma unroll
      for (int s=0;s<16;++s) h[s] = __expf(As[s]*dtv)*h[s] + dtx*Bv[s];
    }
  }
  {
    int base = (c*16 + dl)*17;
    #pragma unroll
    for (int s=0;s<16;++s) Ul[base + s] = h[s];
    Sl[c*16 + dl] = sdt;
  }
  __syncthreads();
  if (tid < 256){
    int dl2 = tid >> 4, s2 = tid & 15;
    float A2 = Amat[(dg*16 + dl2)*16 + s2];
    float hh = 0.f;
    for (int cc = 0; cc < 32; ++cc){
      float u = Ul[(cc*16 + dl2)*17 + s2];
      float ss = Sl[cc*16 + dl2];
      hh = __expf(A2*ss)*hh + u;
      Ul[(cc*16 + dl2)*17 + s2] = hh;
    }
  }
  __syncthreads();
  if (c == 0){
    #pragma unroll
    for (int s=0;s<16;++s) h[s] = 0.f;
  } else {
    int base = ((c-1)*16 + dl)*17;
    #pragma unroll
    for (int s=0;s<16;++s) h[s] = Ul[base + s];
  }
  float Dd = Dw[d];
  if (fast){
    for (int i = 0; i < 18; ++i){
      size_t m = (size_t)(tbase + i);
      float dtv = b2f(dt[m*96 + d]);
      float xv = b2f(xsb[m*96 + d]);
      float dtx = dtv * xv;
      const uint4* bp = (const uint4*)(bc + m*32);
      float Bv[16], Cv[16];
      unpack8(bp[0], Bv); unpack8(bp[1], Bv+8);
      unpack8(bp[2], Cv); unpack8(bp[3], Cv+8);
      float w1=__expf(-dtv), w2=w1*w1, w3=w2*w1, w4=w2*w2;
      float w5=w4*w1, w6=w4*w2, w7=w4*w3, w8=w4*w4;
      float w9=w8*w1, w10=w8*w2, w11=w8*w3, w12=w8*w4;
      float w13=w8*w5, w14=w8*w6, w15=w8*w7, w16=w8*w8;
      float dA[16]={w1,w2,w3,w4,w5,w6,w7,w8,w9,w10,w11,w12,w13,w14,w15,w16};
      float p0=0.f,p1=0.f,p2=0.f,p3=0.f;
      #pragma unroll
      for (int s=0;s<16;s+=4){
        h[s+0] = dA[s+0]*h[s+0] + dtx*Bv[s+0]; p0 += h[s+0]*Cv[s+0];
        h[s+1] = dA[s+1]*h[s+1] + dtx*Bv[s+1]; p1 += h[s+1]*Cv[s+1];
        h[s+2] = dA[s+2]*h[s+2] + dtx*Bv[s+2]; p2 += h[s+2]*Cv[s+2];
        h[s+3] = dA[s+3]*h[s+3] + dtx*Bv[s+3]; p3 += h[s+3]*Cv[s+3];
      }
      float y = (p0+p1) + (p2+p3);
      y2[m*96 + d] = f2b(y + Dd*xv);
    }
  } else {
    for (int i = 0; i < 18; ++i){
      size_t m = (size_t)(tbase + i);
      float dtv = b2f(dt[m*96 + d]);
      float xv = b2f(xsb[m*96 + d]);
      float dtx = dtv * xv;
      const uint4* bp = (const uint4*)(bc + m*32);
      float Bv[16], Cv[16];
      unpack8(bp[0], Bv); unpack8(bp[1], Bv+8);
      unpack8(bp[2], Cv); unpack8(bp[3], Cv+8);
      float p0=0.f,p1=0.f,p2=0.f,p3=0.f;
      #pragma unroll
      for (int s=0;s<16;s+=4){
        h[s+0] = __expf(As[s+0]*dtv)*h[s+0] + dtx*Bv[s+0]; p0 += h[s+0]*Cv[s+0];
        h[s+1] = __expf(As[s+1]*dtv)*h[s+1] + dtx*Bv[s+1]; p1 += h[s+1]*Cv[s+1];
        h[s+2] = __expf(As[s+2]*dtv)*h[s+2] + dtx*Bv[s+2]; p2 += h[s+2]*Cv[s+2];
        h[s+3] = __expf(As[s+3]*dtv)*h[s+3] + dtx*Bv[s+3]; p3 += h[s+3]*Cv[s+3];
      }
      float y = (p0+p1) + (p2+p3);
      y2[m*96 + d] = f2b(y + Dd*xv);
    }
  }
}

// ---------------- head: depthwise 3x3 + BN + silu + linear heads ----------------
__global__ __launch_bounds__(256) void k_head(const float* __restrict__ tokens,
    const float* __restrict__ hdw, const float* __restrict__ bng,
    const float* __restrict__ bnb, const float* __restrict__ bnm,
    const float* __restrict__ bnv, const float* __restrict__ Wheat,
    const float* __restrict__ bheat, const float* __restrict__ Woff,
    const float* __restrict__ boff, const float* __restrict__ Wsize,
    const float* __restrict__ bsize, float* __restrict__ out)
{
  __shared__ float ft[3*2304];
  __shared__ float act[2304];
  int b = blockIdx.x / 24; int h = blockIdx.x - b*24;
  for (int i = threadIdx.x; i < 3*2304; i += 256){
    int rr = i / 2304; int j = i - rr*2304;
    int hh = h + rr - 1;
    float v = 0.f;
    if (hh >= 0 && hh < 24) v = tokens[((size_t)b*576 + hh*24)*96 + j];
    ft[rr*2304 + j] = v;
  }
  __syncthreads();
  for (int i = threadIdx.x; i < 2304; i += 256){
    int w = i / 96; int cc = i - w*96;
    float g = 0.f;
    #pragma unroll
    for (int dh = 0; dh < 3; ++dh){
      #pragma unroll
      for (int dw = 0; dw < 3; ++dw){
        int ww = w + dw - 1;
        if (ww >= 0 && ww < 24) g += ft[dh*2304 + ww*96 + cc] * hdw[cc*9 + dh*3 + dw];
      }
    }
    float gn = (g - bnm[cc]) * rsqrtf(bnv[cc] + 1e-5f);
    float a = gn * bng[cc] + bnb[cc];
    act[i] = a * sigf(a);
  }
  __syncthreads();
  int tid = threadIdx.x;
  if (tid < 120){
    int o = tid / 24; int w = tid - o*24;
    float s = 0.f;
    for (int cc = 0; cc < 96; ++cc) s += act[w*96 + cc] * Wheat[o*96 + cc];
    s += bheat[o];
    out[(size_t)b*2880 + o*576 + h*24 + w] = s;
  } else if (tid >= 128 && tid < 224){
    int idx = tid - 128; int o2 = idx / 24; int w = idx - o2*24;
    const float* W = (o2 < 2) ? Woff : Wsize;
    int o = o2 & 1;
    float s = 0.f;
    for (int cc = 0; cc < 96; ++cc) s += ft[2304 + w*96 + cc] * W[o*96 + cc];
    s += ((o2 < 2) ? boff : bsize)[o];
    size_t baseo = (o2 < 2) ? (size_t)184320 : (size_t)258048;
    out[baseo + (size_t)b*1152 + o*576 + h*24 + w] = s;
  }
}

// ---------------- host ----------------
extern "C" void kernel_launch(void* const* d_in, const int* in_sizes, int n_in,
                              void* d_out, int out_size, void* d_ws, size_t ws_size,
                              hipStream_t stream)
{
  (void)in_sizes; (void)n_in; (void)out_size;
  const float* x      = (const float*)d_in[0];
  const float* Wpe    = (const float*)d_in[1];
  const float* bpe    = (const float*)d_in[2];
  const float* Wvis   = (const float*)d_in[3];
  const float* bvis   = (const float*)d_in[4];
  const float* dng    = (const float*)d_in[5];
  const float* dnb    = (const float*)d_in[6];
  const float* Wgate  = (const float*)d_in[7];
  const float* bgate  = (const float*)d_in[8];
  const float* lng    = (const float*)d_in[9];
  const float* lnb    = (const float*)d_in[10];
  const float* Win    = (const float*)d_in[11];
  const float* convw  = (const float*)d_in[12];
  const float* Wxproj = (const float*)d_in[13];
  const float* Wdt    = (const float*)d_in[14];
  const float* bdt    = (const float*)d_in[15];
  const float* Alog   = (const float*)d_in[16];
  const float* Dw     = (const float*)d_in[17];
  const float* Wout   = (const float*)d_in[18];
  const float* hddw   = (const float*)d_in[19];
  const float* bng    = (const float*)d_in[20];
  const float* bnb    = (const float*)d_in[21];
  const float* bnm    = (const float*)d_in[22];
  const float* bnv    = (const float*)d_in[23];
  const float* Wheat  = (const float*)d_in[24];
  const float* bheat  = (const float*)d_in[25];
  const float* Woff   = (const float*)d_in[26];
  const float* boff   = (const float*)d_in[27];
  const float* Wsize  = (const float*)d_in[28];
  const float* bsize  = (const float*)d_in[29];
  float* out = (float*)d_out;

  const bool big = ws_size >= (size_t)120324096;
  char* ws = (char*)d_ws;

  size_t o_xlog = 0;
  size_t o_tok  = 56623104;
  size_t o_vis  = 70778880;
  size_t o_wgt  = 70926336;
  size_t o_wit  = 70944768;
  size_t o_wxt  = 70981632;
  size_t o_wot  = 71006208;
  size_t o_amat = 71024640;
  size_t o_wpe  = 71030784;
  size_t o_cw   = 71178240;
  size_t o_gate, o_xin, o_zsv, o_xsb, o_y2, o_dt, o_bc;
  if (big){
    o_gate = 75497472;  o_xin = 82575360;  o_zsv = 89653248;
    o_xsb  = 96731136;  o_y2  = 103809024; o_dt  = 110886912; o_bc = 117964800;
  } else {
    o_bc   = 0;         o_gate = 14155776; o_xsb = 21233664;
    o_y2   = 28311552;  o_xin  = 35389440; o_zsv = 42467328;  o_dt = 49545216;
  }

  unsigned short* xlog  = (unsigned short*)(ws + o_xlog);
  float*          tok   = (float*)(ws + o_tok);
  float*          vis   = (float*)(ws + o_vis);
  unsigned short* WgT   = (unsigned short*)(ws + o_wgt);
  unsigned short* WiT   = (unsigned short*)(ws + o_wit);
  unsigned short* WxT   = (unsigned short*)(ws + o_wxt);
  unsigned short* WoT   = (unsigned short*)(ws + o_wot);
  float*          Amat  = (float*)(ws + o_amat);
  unsigned short* WpeB  = (unsigned short*)(ws + o_wpe);
  float*          cwsp  = (float*)(ws + o_cw);
  unsigned short* gate  = (unsigned short*)(ws + o_gate);
  unsigned short* xinb  = (unsigned short*)(ws + o_xin);
  unsigned short* zsvb  = (unsigned short*)(ws + o_zsv);
  unsigned short* xsb   = (unsigned short*)(ws + o_xsb);
  unsigned short* y2    = (unsigned short*)(ws + o_y2);
  unsigned short* dtb   = (unsigned short*)(ws + o_dt);
  unsigned short* bcb   = (unsigned short*)(ws + o_bc);

  k_prep<<<128, 256, 0, stream>>>(Wgate, Win, Wxproj, Wdt, Wout, Alog, Wpe, convw,
                                  WgT, WiT, WxT, WoT, Amat, WpeB, cwsp);
  k_blur<<<9216, 256, 0, stream>>>(x, xlog);
  if (big){
    k_patchfull<<<1152, 256, 0, stream>>>(xlog, WpeB, bpe, dng, dnb, Wvis, bvis,
                                          WgT, bgate, lng, lnb, WiT,
                                          tok, gate, vis, xinb, zsvb);
  } else {
    k_patchln<<<576, 256, 0, stream>>>(xlog, WpeB, bpe, dng, dnb, Wvis, bvis, tok, vis);
    k_lnfull<<<1152, 256, 0, stream>>>(tok, WgT, bgate, lng, lnb, WiT, vis,
                                       gate, xinb, zsvb);
  }

  for (int rep = 0; rep < 4; ++rep){
    k_convxp<<<1152, 256, 0, stream>>>(xinb, cwsp, WxT, bdt, xsb, dtb, bcb);
    k_scan<<<384, 512, 0, stream>>>(dtb, xsb, bcb, Amat, Dw, y2);
    if (rep < 3)
      k_woutln<true><<<1152, 256, 0, stream>>>(y2, WoT, gate, lng, lnb, WiT, vis,
                                               tok, xinb, zsvb);
    else
      k_woutln<false><<<1152, 256, 0, stream>>>(y2, WoT, gate, lng, lnb, WiT, vis,
                                                tok, xinb, zsvb);
  }

  k_head<<<1536, 256, 0, stream>>>(tok, hddw, bng, bnb, bnm, bnv,
                                   Wheat, bheat, Woff, boff, Wsize, bsize, out);
}